// Round 10
// baseline (3889.674 us; speedup 1.0000x reference)
//
#include <hip/hip_runtime.h>
#include <math.h>

#define D4   4
#define NB   64      // batch = #filters = #observations
#define T    2048
#define TP1  2049
#define HID  20
#define POS  3
#define CH   256     // chunks for backward parallel scan
#define CLEN 8       // chunk length (CH*CLEN >= T-1)
#define FPB  4       // filters per block in k_filter

// ---- workspace layout (floats) -------------------------------------------
#define OFF_XHAT  0
#define OFF_SIGMA (TP1*NB*4)
#define OFF_FR    (2*TP1*NB*4)
#define OFF_C     (OFF_FR + T*NB*16)
#define OFF_E     (OFF_C + NB*CH*36)

// ---- DPP wave reductions (VALU pipe, no LDS) ------------------------------
template<int CTRL, int RM>
__device__ __forceinline__ float dpp_sum_step(float v) {
  int t = __builtin_amdgcn_update_dpp(0, __float_as_int(v), CTRL, RM, 0xF, true);
  return v + __int_as_float(t);
}
// sum across 64 lanes; TOTAL lands in lane 63 (no broadcast)
__device__ __forceinline__ float wsum_v(float v) {
  v = dpp_sum_step<0x111, 0xF>(v);   // row_shr:1
  v = dpp_sum_step<0x112, 0xF>(v);   // row_shr:2
  v = dpp_sum_step<0x114, 0xF>(v);   // row_shr:4
  v = dpp_sum_step<0x118, 0xF>(v);   // row_shr:8
  v = dpp_sum_step<0x142, 0xA>(v);   // row_bcast:15 into rows 1,3
  v = dpp_sum_step<0x143, 0xC>(v);   // row_bcast:31 into rows 2,3
  return v;
}
__device__ __forceinline__ float rdlane(float v, int l) {
  return __int_as_float(__builtin_amdgcn_readlane(__float_as_int(v), l));
}

// ---- 4x4 inverse (adjugate, general); returns det ------------------------
__device__ __forceinline__ float inv4(const float a[4][4], float inv[4][4]) {
  float s0 = a[0][0]*a[1][1] - a[1][0]*a[0][1];
  float s1 = a[0][0]*a[1][2] - a[1][0]*a[0][2];
  float s2 = a[0][0]*a[1][3] - a[1][0]*a[0][3];
  float s3 = a[0][1]*a[1][2] - a[1][1]*a[0][2];
  float s4 = a[0][1]*a[1][3] - a[1][1]*a[0][3];
  float s5 = a[0][2]*a[1][3] - a[1][2]*a[0][3];
  float c5 = a[2][2]*a[3][3] - a[3][2]*a[2][3];
  float c4 = a[2][1]*a[3][3] - a[3][1]*a[2][3];
  float c3 = a[2][1]*a[3][2] - a[3][1]*a[2][2];
  float c2 = a[2][0]*a[3][3] - a[3][0]*a[2][3];
  float c1 = a[2][0]*a[3][2] - a[3][0]*a[2][2];
  float c0 = a[2][0]*a[3][1] - a[3][0]*a[2][1];
  float det = s0*c5 - s1*c4 + s2*c3 + s3*c2 - s4*c1 + s5*c0;
  float id = __fdividef(1.0f, det);
  inv[0][0] = ( a[1][1]*c5 - a[1][2]*c4 + a[1][3]*c3) * id;
  inv[0][1] = (-a[0][1]*c5 + a[0][2]*c4 - a[0][3]*c3) * id;
  inv[0][2] = ( a[3][1]*s5 - a[3][2]*s4 + a[3][3]*s3) * id;
  inv[0][3] = (-a[2][1]*s5 + a[2][2]*s4 - a[2][3]*s3) * id;
  inv[1][0] = (-a[1][0]*c5 + a[1][2]*c2 - a[1][3]*c1) * id;
  inv[1][1] = ( a[0][0]*c5 - a[0][2]*c2 + a[0][3]*c1) * id;
  inv[1][2] = (-a[3][0]*s5 + a[3][2]*s2 - a[3][3]*s1) * id;
  inv[1][3] = ( a[2][0]*s5 - a[2][2]*s2 + a[2][3]*s1) * id;
  inv[2][0] = ( a[1][0]*c4 - a[1][1]*c2 + a[1][3]*c0) * id;
  inv[2][1] = (-a[0][0]*c4 + a[0][1]*c2 - a[0][3]*c0) * id;
  inv[2][2] = ( a[3][0]*s4 - a[3][1]*s2 + a[3][3]*s0) * id;
  inv[2][3] = (-a[2][0]*s4 + a[2][1]*s2 - a[2][3]*s0) * id;
  inv[3][0] = (-a[1][0]*c3 + a[1][1]*c1 - a[1][2]*c0) * id;
  inv[3][1] = ( a[0][0]*c3 - a[0][1]*c1 + a[0][2]*c0) * id;
  inv[3][2] = (-a[3][0]*s3 + a[3][1]*s1 - a[3][2]*s0) * id;
  inv[3][3] = ( a[2][0]*s3 - a[2][1]*s1 + a[2][2]*s0) * id;
  return det;
}

// ---- Q = L L^T from q_param (tril_indices row-major order) ---------------
__device__ __forceinline__ void build_Q(const float* __restrict__ qp, float Q[4][4]) {
  float L[4][4] = {{0.f,0.f,0.f,0.f},{0.f,0.f,0.f,0.f},{0.f,0.f,0.f,0.f},{0.f,0.f,0.f,0.f}};
  L[0][0] = expf(qp[0]);
  L[1][0] = qp[1]; L[1][1] = expf(qp[2]);
  L[2][0] = qp[3]; L[2][1] = qp[4]; L[2][2] = expf(qp[5]);
  L[3][0] = qp[6]; L[3][1] = qp[7]; L[3][2] = qp[8]; L[3][3] = expf(qp[9]);
#pragma unroll
  for (int r = 0; r < 4; ++r)
#pragma unroll
    for (int c = 0; c < 4; ++c) {
      float v = 0.f;
#pragma unroll
      for (int k = 0; k < 4; ++k) v += L[r][k] * L[c][k];
      Q[r][c] = v;
    }
}

__device__ __forceinline__ void load_A_b_Q(const float* __restrict__ Ag,
                                           const float* __restrict__ bg,
                                           const float* __restrict__ qp,
                                           float A[4][4], float b[4], float Q[4][4]) {
#pragma unroll
  for (int r = 0; r < 4; ++r) {
    b[r] = bg[r];
#pragma unroll
    for (int c = 0; c < 4; ++c) A[r][c] = Ag[r * 4 + c];
  }
  build_Q(qp, Q);
}

// reconstruct filtered (mf, Pf) from raw moments {W, wm, q}
__device__ __forceinline__ void load_state_raw(const float* __restrict__ p,
                                               float mf[4], float Pf[4][4]) {
  float4 r0 = *(const float4*)&p[0];
  float4 r1 = *(const float4*)&p[4];
  float4 r2 = *(const float4*)&p[8];
  float4 r3 = *(const float4*)&p[12];
  float rW = __fdividef(1.0f, r0.x);
  mf[0]=r0.y*rW; mf[1]=r0.z*rW; mf[2]=r0.w*rW; mf[3]=r1.x*rW;
  Pf[0][0]=fmaf(r1.y,rW,-mf[0]*mf[0]);
  Pf[0][1]=fmaf(r1.z,rW,-mf[0]*mf[1]); Pf[1][0]=Pf[0][1];
  Pf[0][2]=fmaf(r1.w,rW,-mf[0]*mf[2]); Pf[2][0]=Pf[0][2];
  Pf[0][3]=fmaf(r2.x,rW,-mf[0]*mf[3]); Pf[3][0]=Pf[0][3];
  Pf[1][1]=fmaf(r2.y,rW,-mf[1]*mf[1]);
  Pf[1][2]=fmaf(r2.z,rW,-mf[1]*mf[2]); Pf[2][1]=Pf[1][2];
  Pf[1][3]=fmaf(r2.w,rW,-mf[1]*mf[3]); Pf[3][1]=Pf[1][3];
  Pf[2][2]=fmaf(r3.x,rW,-mf[2]*mf[2]);
  Pf[2][3]=fmaf(r3.y,rW,-mf[2]*mf[3]); Pf[3][2]=Pf[2][3];
  Pf[3][3]=fmaf(r3.z,rW,-mf[3]*mf[3]);
}

// ==========================================================================
// K1: encoder
// ==========================================================================
__global__ void k_encoder(const float* __restrict__ x,
                          const float* __restrict__ w1, const float* __restrict__ b1,
                          const float* __restrict__ wx, const float* __restrict__ bx,
                          const float* __restrict__ wl, const float* __restrict__ bl,
                          float* __restrict__ xhat, float* __restrict__ sigma) {
  int idx = blockIdx.x * blockDim.x + threadIdx.x;
  if (idx >= TP1 * NB) return;
  float x0 = x[idx*3+0], x1 = x[idx*3+1], x2 = x[idx*3+2];
  float xh[4], lm[4];
#pragma unroll
  for (int k = 0; k < 4; ++k) { xh[k] = bx[k]; lm[k] = bl[k]; }
#pragma unroll
  for (int j = 0; j < HID; ++j) {
    float h = x0*w1[0*HID+j] + x1*w1[1*HID+j] + x2*w1[2*HID+j] + b1[j];
    h = fmaxf(h, 0.0f);
#pragma unroll
    for (int k = 0; k < 4; ++k) { xh[k] += h * wx[j*4+k]; lm[k] += h * wl[j*4+k]; }
  }
  *(float4*)&xhat[(size_t)idx*4]  = make_float4(xh[0], xh[1], xh[2], xh[3]);
  *(float4*)&sigma[(size_t)idx*4] = make_float4(expf(0.5f*lm[0]), expf(0.5f*lm[1]),
                                                expf(0.5f*lm[2]), expf(0.5f*lm[3]));
}

// ==========================================================================
// K2: forward mixture Kalman filter — 4 filters × 4 waves per 1024-thr block
//   Each SIMD hosts 4 waves from 4 INDEPENDENT filters -> dependency-stall
//   bubbles of one filter's chain are filled by the others (TLP).
//   Per-filter structure identical to round 9.
// ==========================================================================
__global__ void __launch_bounds__(1024, 1) k_filter(
    const float* __restrict__ xhat, const float* __restrict__ sigma,
    const float* __restrict__ Ag, const float* __restrict__ bg,
    const float* __restrict__ qp,
    float* __restrict__ fr) {
  const int tid = threadIdx.x;
  const int lf  = tid >> 8;          // filter-in-block (0..3)
  const int fi  = blockIdx.x * FPB + lf;
  const int wv  = (tid >> 6) & 3;    // wave-in-filter (0..3)
  const int n   = tid & 63;          // observation lane

  __shared__ __align__(16) float xch[FPB][2][16];

  // ---- per-lane predict-entry setup (once) ----
  int r, c;
  if (n < 10) {
    r = (n < 4) ? 0 : (n < 7) ? 1 : (n < 9) ? 2 : 3;
    c = (n < 4) ? n : (n < 7) ? n - 3 : (n < 9) ? n - 5 : 3;
  } else if (n < 14) { r = n - 10; c = 0; }
  else { r = 0; c = 0; }

  float ar0 = Ag[r*4+0], ar1 = Ag[r*4+1], ar2 = Ag[r*4+2], ar3 = Ag[r*4+3];
  float ac0 = Ag[c*4+0], ac1 = Ag[c*4+1], ac2 = Ag[c*4+2], ac3 = Ag[c*4+3];
  float qmask = (n < 10) ? 1.0f : 0.0f;
  float pmask = (n >= 10 && n < 14) ? 1.0f : 0.0f;
  float wp0 = (ar0*ac0) * qmask;
  float wp1 = (ar0*ac1 + ar1*ac0) * qmask;
  float wp2 = (ar0*ac2 + ar2*ac0) * qmask;
  float wp3 = (ar0*ac3 + ar3*ac0) * qmask;
  float wp4 = (ar1*ac1) * qmask;
  float wp5 = (ar1*ac2 + ar2*ac1) * qmask;
  float wp6 = (ar1*ac3 + ar3*ac1) * qmask;
  float wp7 = (ar2*ac2) * qmask;
  float wp8 = (ar2*ac3 + ar3*ac2) * qmask;
  float wp9 = (ar3*ac3) * qmask;

  float initv;   // lanes<10: Q_e ; lanes 10-13: b_r ; else 0
  {
    int trir = r*(r+1)/2, tric = c*(c+1)/2;
    float Lr[4], Lc[4];
#pragma unroll
    for (int k = 0; k < 4; ++k) {
      Lr[k] = (k > r) ? 0.0f : (k == r ? expf(qp[trir+r]) : qp[trir+k]);
      Lc[k] = (k > c) ? 0.0f : (k == c ? expf(qp[tric+c]) : qp[tric+k]);
    }
    float Qe = Lr[0]*Lc[0] + Lr[1]*Lc[1] + Lr[2]*Lc[2] + Lr[3]*Lc[3];
    if (n < 10)      initv = Qe;
    else if (n < 14) initv = bg[n-10];
    else             initv = 0.0f;
  }

  // ---- seed raw state: W=1, wm=m0, q = P0 + m0 m0^T (P0 = diag(s0)) ----
  float4 A0, A1, A2, A3;
  {
    float4 m0 = *(const float4*)&xhat[fi*4];
    float4 s0 = *(const float4*)&sigma[fi*4];
    A0 = make_float4(1.0f, m0.x, m0.y, m0.z);
    A1 = make_float4(m0.w,
                     fmaf(m0.x, m0.x, s0.x), m0.x*m0.y, m0.x*m0.z);
    A2 = make_float4(m0.x*m0.w,
                     fmaf(m0.y, m0.y, s0.y), m0.y*m0.z, m0.y*m0.w);
    A3 = make_float4(fmaf(m0.z, m0.z, s0.z), m0.z*m0.w,
                     fmaf(m0.w, m0.w, s0.w), 0.0f);
  }

  // preload obs row 1 (step t uses row t+1)
  float4 zz  = *(const float4*)&xhat[(size_t)(NB + n)*4];
  float4 sgc = *(const float4*)&sigma[(size_t)(NB + n)*4];

#pragma unroll 2
  for (int t = 0; t < T; ++t) {
    int nr = (t + 2 <= TP1 - 1) ? (t + 2) : (TP1 - 1);
    float4 zn  = *(const float4*)&xhat[((size_t)nr*NB + n)*4];
    float4 sgn = *(const float4*)&sigma[((size_t)nr*NB + n)*4];

    // ---- distributed predict from raw moments ----
    float rW = __fdividef(1.0f, A0.x);
    float dotq =
        ((fmaf(wp0, A1.y, wp1*A1.z) + fmaf(wp2, A1.w, wp3*A2.x)) +
         (fmaf(wp4, A2.y, wp5*A2.z) + fmaf(wp6, A2.w, wp7*A3.x))) +
        fmaf(wp8, A3.y, wp9*A3.z);
    float wdr = fmaf(ar0, A0.y, ar1*A0.z) + fmaf(ar2, A0.w, ar3*A1.x);
    float wdc = fmaf(ac0, A0.y, ac1*A0.z) + fmaf(ac2, A0.w, ac3*A1.x);
    float Amur = wdr * rW, Amuc = wdc * rW;
    float pe = fmaf(dotq, rW, initv);
    pe = fmaf(pmask, Amur, pe);
    pe = fmaf(-qmask, Amur*Amuc, pe);

    float p00 = rdlane(pe, 0), p01 = rdlane(pe, 1), p02 = rdlane(pe, 2), p03 = rdlane(pe, 3);
    float p11 = rdlane(pe, 4), p12 = rdlane(pe, 5), p13 = rdlane(pe, 6);
    float p22 = rdlane(pe, 7), p23 = rdlane(pe, 8), p33 = rdlane(pe, 9);
    float mp0 = rdlane(pe,10), mp1 = rdlane(pe,11), mp2 = rdlane(pe,12), mp3 = rdlane(pe,13);

    // ---- per-lane: S = Pp + diag(sigma); un-normalized adjugate ----
    float s00 = p00 + sgc.x, s11 = p11 + sgc.y, s22 = p22 + sgc.z, s33 = p33 + sgc.w;
    float s01 = p01, s02 = p02, s03 = p03, s12 = p12, s13 = p13, s23 = p23;

    float m0_ = s00*s11 - s01*s01;
    float m1_ = s00*s12 - s01*s02;
    float m2_ = s00*s13 - s01*s03;
    float m3_ = s01*s12 - s11*s02;
    float m4_ = s01*s13 - s11*s03;
    float m5_ = s02*s13 - s12*s03;
    float n5_ = s22*s33 - s23*s23;
    float n4_ = s12*s33 - s13*s23;
    float n3_ = s12*s23 - s13*s22;
    float n2_ = s02*s33 - s03*s23;
    float n1_ = s02*s23 - s03*s22;
    float det = (fmaf(m0_, n5_, -(m1_*n4_)) + fmaf(m2_, n3_, m3_*n2_)) +
                fmaf(m5_, m5_, -(m4_*n1_));
    float rsd = __builtin_amdgcn_rsqf(det);   // det^(-1/2), SPD => det > 0
    float id  = rsd * rsd;                    // 1/det
    float a00_ = ( s11*n5_ - s12*n4_ + s13*n3_);
    float a01_ = (-s01*n5_ + s02*n4_ - s03*n3_);
    float a02_ = ( s13*m5_ - s23*m4_ + s33*m3_);
    float a03_ = (-s12*m5_ + s22*m4_ - s23*m3_);
    float a11_ = ( s00*n5_ - s02*n2_ + s03*n1_);
    float a12_ = (-s03*m5_ + s23*m2_ - s33*m1_);
    float a13_ = ( s02*m5_ - s22*m2_ + s23*m1_);
    float a22_ = ( s03*m4_ - s13*m2_ + s33*m0_);
    float a23_ = (-s02*m4_ + s12*m2_ - s23*m0_);
    float a33_ = ( s02*m3_ - s12*m1_ + s22*m0_);

    float iv0 = zz.x - mp0, iv1 = zz.y - mp1, iv2 = zz.z - mp2, iv3 = zz.w - mp3;
    float ya0 = fmaf(a00_, iv0, a01_*iv1) + fmaf(a02_, iv2, a03_*iv3);
    float ya1 = fmaf(a01_, iv0, a11_*iv1) + fmaf(a12_, iv2, a13_*iv3);
    float ya2 = fmaf(a02_, iv0, a12_*iv1) + fmaf(a22_, iv2, a23_*iv3);
    float ya3 = fmaf(a03_, iv0, a13_*iv1) + fmaf(a23_, iv2, a33_*iv3);
    float quad = (fmaf(iv0, ya0, iv1*ya1) + fmaf(iv2, ya2, iv3*ya3)) * id;

    // softmax weight up to a wave-constant factor (cancels in normalize)
    float wi = __expf(-0.5f * quad) * rsd;

    // diagonal-R identity: mi = z − σ∘y  (y = S⁻¹ iv = ya·id)
    float y0 = ya0*id, y1 = ya1*id, y2 = ya2*id, y3 = ya3*id;
    float mi0 = fmaf(-sgc.x, y0, zz.x);
    float mi1 = fmaf(-sgc.y, y1, zz.y);
    float mi2 = fmaf(-sgc.z, y2, zz.z);
    float mi3 = fmaf(-sgc.w, y3, zz.w);

    const int par = t & 1;
    float* lb = xch[lf][par];

    if (wv == 0) {
      // chains: W, wm0-3
      float cW  = wsum_v(wi);
      float cm0 = wsum_v(wi*mi0);
      float cm1 = wsum_v(wi*mi1);
      float cm2 = wsum_v(wi*mi2);
      float cm3 = wsum_v(wi*mi3);
      if (n == 63) {
        *(float4*)&lb[0] = make_float4(cW, cm0, cm1, cm2);
        lb[4] = cm3;
      }
    } else if (wv == 1) {
      // chains: q00,q01,q02,q03 ; X_rc = δσ − σ_r σ_c id a_rc + mi_r mi_c
      float t0 = sgc.x * id;
      float X00 = fmaf(mi0, mi0, sgc.x) - (t0*sgc.x)*a00_;
      float X01 = fmaf(mi0, mi1, -(t0*sgc.y)*a01_);
      float X02 = fmaf(mi0, mi2, -(t0*sgc.z)*a02_);
      float X03 = fmaf(mi0, mi3, -(t0*sgc.w)*a03_);
      float c00 = wsum_v(wi*X00);
      float c01 = wsum_v(wi*X01);
      float c02 = wsum_v(wi*X02);
      float c03 = wsum_v(wi*X03);
      if (n == 63) { lb[5]=c00; lb[6]=c01; lb[7]=c02; lb[8]=c03; }
    } else if (wv == 2) {
      // chains: q11,q12,q13
      float t1 = sgc.y * id;
      float X11 = fmaf(mi1, mi1, sgc.y) - (t1*sgc.y)*a11_;
      float X12 = fmaf(mi1, mi2, -(t1*sgc.z)*a12_);
      float X13 = fmaf(mi1, mi3, -(t1*sgc.w)*a13_);
      float c11 = wsum_v(wi*X11);
      float c12 = wsum_v(wi*X12);
      float c13 = wsum_v(wi*X13);
      if (n == 63) { lb[9]=c11; lb[10]=c12; lb[11]=c13; }
    } else {
      // chains: q22,q23,q33
      float t2 = sgc.z * id;
      float t3 = sgc.w * id;
      float X22 = fmaf(mi2, mi2, sgc.z) - (t2*sgc.z)*a22_;
      float X23 = fmaf(mi2, mi3, -(t2*sgc.w)*a23_);
      float X33 = fmaf(mi3, mi3, sgc.w) - (t3*sgc.w)*a33_;
      float c22 = wsum_v(wi*X22);
      float c23 = wsum_v(wi*X23);
      float c33 = wsum_v(wi*X33);
      if (n == 63) {
        *(float2*)&lb[12] = make_float2(c22, c23);
        lb[14] = c33;
      }
    }

    __syncthreads();

    A0 = *(const float4*)&xch[lf][par][0];
    A1 = *(const float4*)&xch[lf][par][4];
    A2 = *(const float4*)&xch[lf][par][8];
    A3 = *(const float4*)&xch[lf][par][12];

    if (wv == 0 && n == 0) {
      float* fp = &fr[((size_t)t*NB + fi)*16];
      *(float4*)&fp[0]  = A0;
      *(float4*)&fp[4]  = A1;
      *(float4*)&fp[8]  = A2;
      *(float4*)&fp[12] = A3;
    }
    zz = zn; sgc = sgn;
  }
}

// ==========================================================================
// Backward smoother as an affine suffix scan
// ==========================================================================
struct Map { float G[4][4]; float c[4]; float Dm[4][4]; };

__device__ __forceinline__ void map_identity(Map& M) {
#pragma unroll
  for (int r = 0; r < 4; ++r) {
    M.c[r] = 0.f;
#pragma unroll
    for (int cc = 0; cc < 4; ++cc) { M.G[r][cc] = (r==cc)?1.f:0.f; M.Dm[r][cc] = 0.f; }
  }
}

// R = F ∘ S (apply S first, then F); R may alias either arg
__device__ __forceinline__ void compose(const Map& F, const Map& Sm, Map& R) {
  float G[4][4], cv[4], V[4][4], Dn[4][4];
#pragma unroll
  for (int r = 0; r < 4; ++r)
#pragma unroll
    for (int c = 0; c < 4; ++c)
      G[r][c] = F.G[r][0]*Sm.G[0][c] + F.G[r][1]*Sm.G[1][c]
              + F.G[r][2]*Sm.G[2][c] + F.G[r][3]*Sm.G[3][c];
#pragma unroll
  for (int r = 0; r < 4; ++r)
    cv[r] = F.c[r] + F.G[r][0]*Sm.c[0] + F.G[r][1]*Sm.c[1]
                   + F.G[r][2]*Sm.c[2] + F.G[r][3]*Sm.c[3];
#pragma unroll
  for (int r = 0; r < 4; ++r)
#pragma unroll
    for (int c = 0; c < 4; ++c)
      V[r][c] = F.G[r][0]*Sm.Dm[0][c] + F.G[r][1]*Sm.Dm[1][c]
              + F.G[r][2]*Sm.Dm[2][c] + F.G[r][3]*Sm.Dm[3][c];
#pragma unroll
  for (int r = 0; r < 4; ++r)
#pragma unroll
    for (int c = r; c < 4; ++c) {
      float v = F.Dm[r][c] + V[r][0]*F.G[c][0] + V[r][1]*F.G[c][1]
                           + V[r][2]*F.G[c][2] + V[r][3]*F.G[c][3];
      Dn[r][c] = v; Dn[c][r] = v;
    }
#pragma unroll
  for (int r = 0; r < 4; ++r) {
    R.c[r] = cv[r];
#pragma unroll
    for (int c = 0; c < 4; ++c) { R.G[r][c] = G[r][c]; R.Dm[r][c] = Dn[r][c]; }
  }
}

// per-step map f_t for filter i (from raw forward results)
__device__ __forceinline__ void make_ft(int t, int i,
    const float* __restrict__ fr,
    const float A[4][4], const float b[4], const float Q[4][4], Map& M) {
  float mf[4], Pf[4][4];
  load_state_raw(&fr[((size_t)t*NB + i)*16], mf, Pf);
  float mp[4];
#pragma unroll
  for (int r = 0; r < 4; ++r)
    mp[r] = b[r] + A[r][0]*mf[0] + A[r][1]*mf[1] + A[r][2]*mf[2] + A[r][3]*mf[3];
  float AP[4][4];
#pragma unroll
  for (int r = 0; r < 4; ++r)
#pragma unroll
    for (int c = 0; c < 4; ++c)
      AP[r][c] = A[r][0]*Pf[0][c] + A[r][1]*Pf[1][c] + A[r][2]*Pf[2][c] + A[r][3]*Pf[3][c];
  float Pp[4][4];
#pragma unroll
  for (int r = 0; r < 4; ++r)
#pragma unroll
    for (int c = r; c < 4; ++c) {
      float v = Q[r][c] + AP[r][0]*A[c][0] + AP[r][1]*A[c][1]
                        + AP[r][2]*A[c][2] + AP[r][3]*A[c][3];
      Pp[r][c] = v; Pp[c][r] = v;
    }
  float Ppi[4][4];
  inv4(Pp, Ppi);
  float W[4][4]; // Pf A^T
#pragma unroll
  for (int r = 0; r < 4; ++r)
#pragma unroll
    for (int c = 0; c < 4; ++c)
      W[r][c] = Pf[r][0]*A[c][0] + Pf[r][1]*A[c][1] + Pf[r][2]*A[c][2] + Pf[r][3]*A[c][3];
#pragma unroll
  for (int r = 0; r < 4; ++r)
#pragma unroll
    for (int c = 0; c < 4; ++c)
      M.G[r][c] = W[r][0]*Ppi[0][c] + W[r][1]*Ppi[1][c] + W[r][2]*Ppi[2][c] + W[r][3]*Ppi[3][c];
#pragma unroll
  for (int r = 0; r < 4; ++r)
    M.c[r] = mf[r] - (M.G[r][0]*mp[0] + M.G[r][1]*mp[1] + M.G[r][2]*mp[2] + M.G[r][3]*mp[3]);
  float V[4][4];
#pragma unroll
  for (int r = 0; r < 4; ++r)
#pragma unroll
    for (int c = 0; c < 4; ++c)
      V[r][c] = M.G[r][0]*Pp[0][c] + M.G[r][1]*Pp[1][c] + M.G[r][2]*Pp[2][c] + M.G[r][3]*Pp[3][c];
#pragma unroll
  for (int r = 0; r < 4; ++r)
#pragma unroll
    for (int c = r; c < 4; ++c) {
      float v = Pf[r][c] - (V[r][0]*M.G[c][0] + V[r][1]*M.G[c][1]
                          + V[r][2]*M.G[c][2] + V[r][3]*M.G[c][3]);
      M.Dm[r][c] = v; M.Dm[c][r] = v;
    }
}

__device__ __forceinline__ void store_map(float* __restrict__ p, const Map& M) {
  *(float4*)&p[0]  = make_float4(M.G[0][0],M.G[0][1],M.G[0][2],M.G[0][3]);
  *(float4*)&p[4]  = make_float4(M.G[1][0],M.G[1][1],M.G[1][2],M.G[1][3]);
  *(float4*)&p[8]  = make_float4(M.G[2][0],M.G[2][1],M.G[2][2],M.G[2][3]);
  *(float4*)&p[12] = make_float4(M.G[3][0],M.G[3][1],M.G[3][2],M.G[3][3]);
  *(float4*)&p[16] = make_float4(M.c[0],M.c[1],M.c[2],M.c[3]);
  *(float4*)&p[20] = make_float4(M.Dm[0][0],M.Dm[0][1],M.Dm[0][2],M.Dm[0][3]);
  *(float4*)&p[24] = make_float4(M.Dm[1][0],M.Dm[1][1],M.Dm[1][2],M.Dm[1][3]);
  *(float4*)&p[28] = make_float4(M.Dm[2][0],M.Dm[2][1],M.Dm[2][2],M.Dm[2][3]);
  *(float4*)&p[32] = make_float4(M.Dm[3][0],M.Dm[3][1],M.Dm[3][2],M.Dm[3][3]);
}
__device__ __forceinline__ void load_map(const float* __restrict__ p, Map& M) {
  float4 g0=*(const float4*)&p[0], g1=*(const float4*)&p[4],
         g2=*(const float4*)&p[8], g3=*(const float4*)&p[12];
  float4 cv=*(const float4*)&p[16];
  float4 d0=*(const float4*)&p[20], d1=*(const float4*)&p[24],
         d2=*(const float4*)&p[28], d3=*(const float4*)&p[32];
  M.G[0][0]=g0.x;M.G[0][1]=g0.y;M.G[0][2]=g0.z;M.G[0][3]=g0.w;
  M.G[1][0]=g1.x;M.G[1][1]=g1.y;M.G[1][2]=g1.z;M.G[1][3]=g1.w;
  M.G[2][0]=g2.x;M.G[2][1]=g2.y;M.G[2][2]=g2.z;M.G[2][3]=g2.w;
  M.G[3][0]=g3.x;M.G[3][1]=g3.y;M.G[3][2]=g3.z;M.G[3][3]=g3.w;
  M.c[0]=cv.x;M.c[1]=cv.y;M.c[2]=cv.z;M.c[3]=cv.w;
  M.Dm[0][0]=d0.x;M.Dm[0][1]=d0.y;M.Dm[0][2]=d0.z;M.Dm[0][3]=d0.w;
  M.Dm[1][0]=d1.x;M.Dm[1][1]=d1.y;M.Dm[1][2]=d1.z;M.Dm[1][3]=d1.w;
  M.Dm[2][0]=d2.x;M.Dm[2][1]=d2.y;M.Dm[2][2]=d2.z;M.Dm[2][3]=d2.w;
  M.Dm[3][0]=d3.x;M.Dm[3][1]=d3.y;M.Dm[3][2]=d3.z;M.Dm[3][3]=d3.w;
}

// LDS map I/O, stride-37 floats (bank-conflict-free scalar layout)
__device__ __forceinline__ void store_map_lds(float* p, const Map& M) {
#pragma unroll
  for (int r = 0; r < 4; ++r) {
#pragma unroll
    for (int c2 = 0; c2 < 4; ++c2) {
      p[r*4+c2]    = M.G[r][c2];
      p[20+r*4+c2] = M.Dm[r][c2];
    }
    p[16+r] = M.c[r];
  }
}
__device__ __forceinline__ void load_map_lds(const float* p, Map& M) {
#pragma unroll
  for (int r = 0; r < 4; ++r) {
#pragma unroll
    for (int c2 = 0; c2 < 4; ++c2) {
      M.G[r][c2]  = p[r*4+c2];
      M.Dm[r][c2] = p[20+r*4+c2];
    }
    M.c[r] = p[16+r];
  }
}

// K3 phase A: per (chunk, filter) compose chunk aggregate right-to-left
__global__ void __launch_bounds__(64, 1) k_phaseA(
    const float* __restrict__ fr,
    const float* __restrict__ Ag, const float* __restrict__ bg,
    const float* __restrict__ qp, float* __restrict__ Cw) {
  const int cc = blockIdx.x;
  const int i  = threadIdx.x;
  float A[4][4], Q[4][4], b[4];
  load_A_b_Q(Ag, bg, qp, A, b, Q);
  Map agg; map_identity(agg);
  int a = cc * CLEN;
  int bb = a + CLEN - 1; if (bb > T - 2) bb = T - 2;
  for (int t = bb; t >= a; --t) {
    Map f; make_ft(t, i, fr, A, b, Q, f);
    compose(f, agg, agg);
  }
  store_map(&Cw[((size_t)i*CH + cc)*36], agg);
}

// K4 phase B: per filter, parallel Hillis-Steele suffix scan over CH chunks
__global__ void __launch_bounds__(CH, 1) k_phaseB(
    const float* __restrict__ Cw, float* __restrict__ Ew) {
  const int fi = blockIdx.x;
  const int cc = threadIdx.x;
  __shared__ float lds[CH * 37];

  Map M;
  load_map(&Cw[((size_t)fi*CH + cc)*36], M);
  store_map_lds(&lds[cc*37], M);
  __syncthreads();

#pragma unroll
  for (int k = 0; k < 8; ++k) {        // log2(CH) = 8
    int step = 1 << k;
    Map P;
    bool have = (cc + step < CH);
    if (have) load_map_lds(&lds[(cc+step)*37], P);
    __syncthreads();
    if (have) {
      compose(M, P, M);                // M spans [cc, cc+2^{k+1})
      store_map_lds(&lds[cc*37], M);
    }
    __syncthreads();
  }

  Map E;
  if (cc == CH - 1) map_identity(E);
  else              load_map_lds(&lds[(cc+1)*37], E);
  store_map(&Ew[((size_t)fi*CH + cc)*36], E);
}

// cholesky of sP+1e-5 I, z = sm + L eps, out = z @ dec_w + dec_b
__device__ __forceinline__ void recon(int t, int i,
    const float sm[4], const float sP[4][4],
    const float* __restrict__ eps, const float* __restrict__ dw,
    const float* __restrict__ db, float* __restrict__ out) {
  float a00 = sP[0][0]+1e-5f, a11 = sP[1][1]+1e-5f, a22 = sP[2][2]+1e-5f, a33 = sP[3][3]+1e-5f;
  float L00 = sqrtf(a00);
  float r0 = __fdividef(1.0f, L00);
  float L10 = sP[1][0]*r0, L20 = sP[2][0]*r0, L30 = sP[3][0]*r0;
  float L11 = sqrtf(a11 - L10*L10);
  float r1 = __fdividef(1.0f, L11);
  float L21 = (sP[2][1]-L20*L10)*r1, L31 = (sP[3][1]-L30*L10)*r1;
  float L22 = sqrtf(a22 - L20*L20 - L21*L21);
  float r2 = __fdividef(1.0f, L22);
  float L32 = (sP[3][2]-L30*L20-L31*L21)*r2;
  float L33 = sqrtf(a33 - L30*L30 - L31*L31 - L32*L32);
  float4 e = *(const float4*)&eps[((size_t)t*NB + i)*4];
  float z0 = sm[0] + L00*e.x;
  float z1 = sm[1] + L10*e.x + L11*e.y;
  float z2 = sm[2] + L20*e.x + L21*e.y + L22*e.z;
  float z3 = sm[3] + L30*e.x + L31*e.y + L32*e.z + L33*e.w;
#pragma unroll
  for (int p = 0; p < 3; ++p)
    out[((size_t)t*NB + i)*3 + p] =
        db[p] + z0*dw[0*3+p] + z1*dw[1*3+p] + z2*dw[2*3+p] + z3*dw[3*3+p];
}

// K5 phase C: apply exclusive suffix, walk chunk downward emitting recon
__global__ void __launch_bounds__(64, 1) k_phaseC(
    const float* __restrict__ fr,
    const float* __restrict__ Ew,
    const float* __restrict__ Ag, const float* __restrict__ bg,
    const float* __restrict__ qp,
    const float* __restrict__ eps, const float* __restrict__ dw,
    const float* __restrict__ db, float* __restrict__ out) {
  const int cc = blockIdx.x;
  const int i  = threadIdx.x;
  float A[4][4], Q[4][4], b[4];
  load_A_b_Q(Ag, bg, qp, A, b, Q);

  // final filtered state (t = T-1) == final smoothed state
  float mT[4], PT[4][4];
  load_state_raw(&fr[((size_t)(T-1)*NB + i)*16], mT, PT);

  Map E; load_map(&Ew[((size_t)i*CH + cc)*36], E);

  float sm[4], sP[4][4];
#pragma unroll
  for (int r = 0; r < 4; ++r)
    sm[r] = E.c[r] + E.G[r][0]*mT[0] + E.G[r][1]*mT[1] + E.G[r][2]*mT[2] + E.G[r][3]*mT[3];
  {
    float V[4][4];
#pragma unroll
    for (int r = 0; r < 4; ++r)
#pragma unroll
      for (int c = 0; c < 4; ++c)
        V[r][c] = E.G[r][0]*PT[0][c] + E.G[r][1]*PT[1][c] + E.G[r][2]*PT[2][c] + E.G[r][3]*PT[3][c];
#pragma unroll
    for (int r = 0; r < 4; ++r)
#pragma unroll
      for (int c = r; c < 4; ++c) {
        float v = E.Dm[r][c] + V[r][0]*E.G[c][0] + V[r][1]*E.G[c][1]
                             + V[r][2]*E.G[c][2] + V[r][3]*E.G[c][3];
        sP[r][c] = v; sP[c][r] = v;
      }
  }

  if (cc == CH - 1) recon(T - 1, i, mT, PT, eps, dw, db, out);

  int a = cc * CLEN;
  int bb = a + CLEN - 1; if (bb > T - 2) bb = T - 2;
  for (int t = bb; t >= a; --t) {
    Map f; make_ft(t, i, fr, A, b, Q, f);
    float smn[4];
#pragma unroll
    for (int r = 0; r < 4; ++r)
      smn[r] = f.c[r] + f.G[r][0]*sm[0] + f.G[r][1]*sm[1] + f.G[r][2]*sm[2] + f.G[r][3]*sm[3];
    float V[4][4];
#pragma unroll
    for (int r = 0; r < 4; ++r)
#pragma unroll
      for (int c = 0; c < 4; ++c)
        V[r][c] = f.G[r][0]*sP[0][c] + f.G[r][1]*sP[1][c] + f.G[r][2]*sP[2][c] + f.G[r][3]*sP[3][c];
#pragma unroll
    for (int r = 0; r < 4; ++r)
#pragma unroll
      for (int c = r; c < 4; ++c) {
        float v = f.Dm[r][c] + V[r][0]*f.G[c][0] + V[r][1]*f.G[c][1]
                             + V[r][2]*f.G[c][2] + V[r][3]*f.G[c][3];
        sP[r][c] = v; sP[c][r] = v;
      }
    sm[0]=smn[0]; sm[1]=smn[1]; sm[2]=smn[2]; sm[3]=smn[3];
    recon(t, i, sm, sP, eps, dw, db, out);
  }
}

// ==========================================================================
extern "C" void kernel_launch(void* const* d_in, const int* in_sizes, int n_in,
                              void* d_out, int out_size, void* d_ws, size_t ws_size,
                              hipStream_t stream) {
  const float* x   = (const float*)d_in[0];
  const float* eps = (const float*)d_in[1];
  const float* w1  = (const float*)d_in[2];
  const float* b1  = (const float*)d_in[3];
  const float* wx  = (const float*)d_in[4];
  const float* bx  = (const float*)d_in[5];
  const float* wl  = (const float*)d_in[6];
  const float* bl  = (const float*)d_in[7];
  const float* dw  = (const float*)d_in[8];
  const float* db  = (const float*)d_in[9];
  const float* Ag  = (const float*)d_in[10];
  const float* bg  = (const float*)d_in[11];
  const float* qp  = (const float*)d_in[12];

  float* ws    = (float*)d_ws;
  float* xhat  = ws + OFF_XHAT;
  float* sigma = ws + OFF_SIGMA;
  float* fr    = ws + OFF_FR;
  float* Cw    = ws + OFF_C;
  float* Ew    = ws + OFF_E;
  float* out   = (float*)d_out;

  k_encoder<<<(TP1*NB + 255)/256, 256, 0, stream>>>(x, w1, b1, wx, bx, wl, bl, xhat, sigma);
  k_filter<<<NB/FPB, FPB*256, 0, stream>>>(xhat, sigma, Ag, bg, qp, fr);
  k_phaseA<<<CH, NB, 0, stream>>>(fr, Ag, bg, qp, Cw);
  k_phaseB<<<NB, CH, 0, stream>>>(Cw, Ew);
  k_phaseC<<<CH, NB, 0, stream>>>(fr, Ew, Ag, bg, qp, eps, dw, db, out);
}

// Round 11
// 2196.769 us; speedup vs baseline: 1.7706x; 1.7706x over previous
//
#include <hip/hip_runtime.h>
#include <math.h>

#define D4   4
#define NB   64      // batch = #filters = #observations
#define T    2048
#define TP1  2049
#define HID  20
#define POS  3
#define CH   256     // chunks for backward parallel scan
#define CLEN 8       // chunk length (CH*CLEN >= T-1)

// ---- workspace layout (floats) -------------------------------------------
#define OFF_XHAT  0
#define OFF_SIGMA (TP1*NB*4)
#define OFF_FR    (2*TP1*NB*4)
#define OFF_C     (OFF_FR + T*NB*16)
#define OFF_E     (OFF_C + NB*CH*36)

// ---- DPP wave reductions (VALU pipe, no LDS) ------------------------------
template<int CTRL, int RM>
__device__ __forceinline__ float dpp_sum_step(float v) {
  int t = __builtin_amdgcn_update_dpp(0, __float_as_int(v), CTRL, RM, 0xF, true);
  return v + __int_as_float(t);
}
// sum across 64 lanes; TOTAL lands in lane 63 (no broadcast)
__device__ __forceinline__ float wsum_v(float v) {
  v = dpp_sum_step<0x111, 0xF>(v);   // row_shr:1
  v = dpp_sum_step<0x112, 0xF>(v);   // row_shr:2
  v = dpp_sum_step<0x114, 0xF>(v);   // row_shr:4
  v = dpp_sum_step<0x118, 0xF>(v);   // row_shr:8
  v = dpp_sum_step<0x142, 0xA>(v);   // row_bcast:15 into rows 1,3
  v = dpp_sum_step<0x143, 0xC>(v);   // row_bcast:31 into rows 2,3
  return v;
}
__device__ __forceinline__ float rdlane(float v, int l) {
  return __int_as_float(__builtin_amdgcn_readlane(__float_as_int(v), l));
}

// ---- 4x4 inverse (adjugate, general); returns det ------------------------
__device__ __forceinline__ float inv4(const float a[4][4], float inv[4][4]) {
  float s0 = a[0][0]*a[1][1] - a[1][0]*a[0][1];
  float s1 = a[0][0]*a[1][2] - a[1][0]*a[0][2];
  float s2 = a[0][0]*a[1][3] - a[1][0]*a[0][3];
  float s3 = a[0][1]*a[1][2] - a[1][1]*a[0][2];
  float s4 = a[0][1]*a[1][3] - a[1][1]*a[0][3];
  float s5 = a[0][2]*a[1][3] - a[1][2]*a[0][3];
  float c5 = a[2][2]*a[3][3] - a[3][2]*a[2][3];
  float c4 = a[2][1]*a[3][3] - a[3][1]*a[2][3];
  float c3 = a[2][1]*a[3][2] - a[3][1]*a[2][2];
  float c2 = a[2][0]*a[3][3] - a[3][0]*a[2][3];
  float c1 = a[2][0]*a[3][2] - a[3][0]*a[2][2];
  float c0 = a[2][0]*a[3][1] - a[3][0]*a[2][1];
  float det = s0*c5 - s1*c4 + s2*c3 + s3*c2 - s4*c1 + s5*c0;
  float id = __fdividef(1.0f, det);
  inv[0][0] = ( a[1][1]*c5 - a[1][2]*c4 + a[1][3]*c3) * id;
  inv[0][1] = (-a[0][1]*c5 + a[0][2]*c4 - a[0][3]*c3) * id;
  inv[0][2] = ( a[3][1]*s5 - a[3][2]*s4 + a[3][3]*s3) * id;
  inv[0][3] = (-a[2][1]*s5 + a[2][2]*s4 - a[2][3]*s3) * id;
  inv[1][0] = (-a[1][0]*c5 + a[1][2]*c2 - a[1][3]*c1) * id;
  inv[1][1] = ( a[0][0]*c5 - a[0][2]*c2 + a[0][3]*c1) * id;
  inv[1][2] = (-a[3][0]*s5 + a[3][2]*s2 - a[3][3]*s1) * id;
  inv[1][3] = ( a[2][0]*s5 - a[2][2]*s2 + a[2][3]*s1) * id;
  inv[2][0] = ( a[1][0]*c4 - a[1][1]*c2 + a[1][3]*c0) * id;
  inv[2][1] = (-a[0][0]*c4 + a[0][1]*c2 - a[0][3]*c0) * id;
  inv[2][2] = ( a[3][0]*s4 - a[3][1]*s2 + a[3][3]*s0) * id;
  inv[2][3] = (-a[2][0]*s4 + a[2][1]*s2 - a[2][3]*s0) * id;
  inv[3][0] = (-a[1][0]*c3 + a[1][1]*c1 - a[1][2]*c0) * id;
  inv[3][1] = ( a[0][0]*c3 - a[0][1]*c1 + a[0][2]*c0) * id;
  inv[3][2] = (-a[3][0]*s3 + a[3][1]*s1 - a[3][2]*s0) * id;
  inv[3][3] = ( a[2][0]*s3 - a[2][1]*s1 + a[2][2]*s0) * id;
  return det;
}

// ---- Q = L L^T from q_param (tril_indices row-major order) ---------------
__device__ __forceinline__ void build_Q(const float* __restrict__ qp, float Q[4][4]) {
  float L[4][4] = {{0.f,0.f,0.f,0.f},{0.f,0.f,0.f,0.f},{0.f,0.f,0.f,0.f},{0.f,0.f,0.f,0.f}};
  L[0][0] = expf(qp[0]);
  L[1][0] = qp[1]; L[1][1] = expf(qp[2]);
  L[2][0] = qp[3]; L[2][1] = qp[4]; L[2][2] = expf(qp[5]);
  L[3][0] = qp[6]; L[3][1] = qp[7]; L[3][2] = qp[8]; L[3][3] = expf(qp[9]);
#pragma unroll
  for (int r = 0; r < 4; ++r)
#pragma unroll
    for (int c = 0; c < 4; ++c) {
      float v = 0.f;
#pragma unroll
      for (int k = 0; k < 4; ++k) v += L[r][k] * L[c][k];
      Q[r][c] = v;
    }
}

__device__ __forceinline__ void load_A_b_Q(const float* __restrict__ Ag,
                                           const float* __restrict__ bg,
                                           const float* __restrict__ qp,
                                           float A[4][4], float b[4], float Q[4][4]) {
#pragma unroll
  for (int r = 0; r < 4; ++r) {
    b[r] = bg[r];
#pragma unroll
    for (int c = 0; c < 4; ++c) A[r][c] = Ag[r * 4 + c];
  }
  build_Q(qp, Q);
}

// reconstruct filtered (mf, Pf) from raw moments {W, wm, q}
__device__ __forceinline__ void load_state_raw(const float* __restrict__ p,
                                               float mf[4], float Pf[4][4]) {
  float4 r0 = *(const float4*)&p[0];
  float4 r1 = *(const float4*)&p[4];
  float4 r2 = *(const float4*)&p[8];
  float4 r3 = *(const float4*)&p[12];
  float rW = __fdividef(1.0f, r0.x);
  mf[0]=r0.y*rW; mf[1]=r0.z*rW; mf[2]=r0.w*rW; mf[3]=r1.x*rW;
  Pf[0][0]=fmaf(r1.y,rW,-mf[0]*mf[0]);
  Pf[0][1]=fmaf(r1.z,rW,-mf[0]*mf[1]); Pf[1][0]=Pf[0][1];
  Pf[0][2]=fmaf(r1.w,rW,-mf[0]*mf[2]); Pf[2][0]=Pf[0][2];
  Pf[0][3]=fmaf(r2.x,rW,-mf[0]*mf[3]); Pf[3][0]=Pf[0][3];
  Pf[1][1]=fmaf(r2.y,rW,-mf[1]*mf[1]);
  Pf[1][2]=fmaf(r2.z,rW,-mf[1]*mf[2]); Pf[2][1]=Pf[1][2];
  Pf[1][3]=fmaf(r2.w,rW,-mf[1]*mf[3]); Pf[3][1]=Pf[1][3];
  Pf[2][2]=fmaf(r3.x,rW,-mf[2]*mf[2]);
  Pf[2][3]=fmaf(r3.y,rW,-mf[2]*mf[3]); Pf[3][2]=Pf[2][3];
  Pf[3][3]=fmaf(r3.z,rW,-mf[3]*mf[3]);
}

// ==========================================================================
// K1: encoder
// ==========================================================================
__global__ void k_encoder(const float* __restrict__ x,
                          const float* __restrict__ w1, const float* __restrict__ b1,
                          const float* __restrict__ wx, const float* __restrict__ bx,
                          const float* __restrict__ wl, const float* __restrict__ bl,
                          float* __restrict__ xhat, float* __restrict__ sigma) {
  int idx = blockIdx.x * blockDim.x + threadIdx.x;
  if (idx >= TP1 * NB) return;
  float x0 = x[idx*3+0], x1 = x[idx*3+1], x2 = x[idx*3+2];
  float xh[4], lm[4];
#pragma unroll
  for (int k = 0; k < 4; ++k) { xh[k] = bx[k]; lm[k] = bl[k]; }
#pragma unroll
  for (int j = 0; j < HID; ++j) {
    float h = x0*w1[0*HID+j] + x1*w1[1*HID+j] + x2*w1[2*HID+j] + b1[j];
    h = fmaxf(h, 0.0f);
#pragma unroll
    for (int k = 0; k < 4; ++k) { xh[k] += h * wx[j*4+k]; lm[k] += h * wl[j*4+k]; }
  }
  *(float4*)&xhat[(size_t)idx*4]  = make_float4(xh[0], xh[1], xh[2], xh[3]);
  *(float4*)&sigma[(size_t)idx*4] = make_float4(expf(0.5f*lm[0]), expf(0.5f*lm[1]),
                                                expf(0.5f*lm[2]), expf(0.5f*lm[3]));
}

// ==========================================================================
// K2: forward mixture Kalman filter — 8 waves per filter (512-thread block)
//   ONE filter per block (64 blocks = 64 CUs); 2 waves per SIMD from the
//   SAME filter but computing INDEPENDENT chains within a step -> their
//   dependency-stall bubbles interleave (TLP without losing CUs).
//   Chain ownership (15 chains over 8 waves):
//     w0 {W, wm0}  w1 {wm1, wm2}  w2 {wm3, q00}  w3 {q01, q02}
//     w4 {q03, q11} w5 {q12, q13} w6 {q22, q23}  w7 {q33}
//   LDS slots: 0 W | 1-4 wm0-3 | 5 q00 6 q01 7 q02 8 q03 | 9 q11 10 q12
//              11 q13 | 12 q22 13 q23 14 q33 | 15 pad
// ==========================================================================
__global__ void __launch_bounds__(512, 1) k_filter(
    const float* __restrict__ xhat, const float* __restrict__ sigma,
    const float* __restrict__ Ag, const float* __restrict__ bg,
    const float* __restrict__ qp,
    float* __restrict__ fr) {
  const int fi  = blockIdx.x;        // filter
  const int tid = threadIdx.x;
  const int wv  = tid >> 6;          // wave id (0..7)
  const int n   = tid & 63;          // observation lane

  __shared__ __align__(16) float xch[2][16];

  // ---- per-lane predict-entry setup (once) ----
  int r, c;
  if (n < 10) {
    r = (n < 4) ? 0 : (n < 7) ? 1 : (n < 9) ? 2 : 3;
    c = (n < 4) ? n : (n < 7) ? n - 3 : (n < 9) ? n - 5 : 3;
  } else if (n < 14) { r = n - 10; c = 0; }
  else { r = 0; c = 0; }

  float ar0 = Ag[r*4+0], ar1 = Ag[r*4+1], ar2 = Ag[r*4+2], ar3 = Ag[r*4+3];
  float ac0 = Ag[c*4+0], ac1 = Ag[c*4+1], ac2 = Ag[c*4+2], ac3 = Ag[c*4+3];
  float qmask = (n < 10) ? 1.0f : 0.0f;
  float pmask = (n >= 10 && n < 14) ? 1.0f : 0.0f;
  float wp0 = (ar0*ac0) * qmask;
  float wp1 = (ar0*ac1 + ar1*ac0) * qmask;
  float wp2 = (ar0*ac2 + ar2*ac0) * qmask;
  float wp3 = (ar0*ac3 + ar3*ac0) * qmask;
  float wp4 = (ar1*ac1) * qmask;
  float wp5 = (ar1*ac2 + ar2*ac1) * qmask;
  float wp6 = (ar1*ac3 + ar3*ac1) * qmask;
  float wp7 = (ar2*ac2) * qmask;
  float wp8 = (ar2*ac3 + ar3*ac2) * qmask;
  float wp9 = (ar3*ac3) * qmask;

  float initv;   // lanes<10: Q_e ; lanes 10-13: b_r ; else 0
  {
    int trir = r*(r+1)/2, tric = c*(c+1)/2;
    float Lr[4], Lc[4];
#pragma unroll
    for (int k = 0; k < 4; ++k) {
      Lr[k] = (k > r) ? 0.0f : (k == r ? expf(qp[trir+r]) : qp[trir+k]);
      Lc[k] = (k > c) ? 0.0f : (k == c ? expf(qp[tric+c]) : qp[tric+k]);
    }
    float Qe = Lr[0]*Lc[0] + Lr[1]*Lc[1] + Lr[2]*Lc[2] + Lr[3]*Lc[3];
    if (n < 10)      initv = Qe;
    else if (n < 14) initv = bg[n-10];
    else             initv = 0.0f;
  }

  // ---- seed raw state: W=1, wm=m0, q = P0 + m0 m0^T (P0 = diag(s0)) ----
  float4 A0, A1, A2, A3;
  {
    float4 m0 = *(const float4*)&xhat[fi*4];
    float4 s0 = *(const float4*)&sigma[fi*4];
    A0 = make_float4(1.0f, m0.x, m0.y, m0.z);
    A1 = make_float4(m0.w,
                     fmaf(m0.x, m0.x, s0.x), m0.x*m0.y, m0.x*m0.z);
    A2 = make_float4(m0.x*m0.w,
                     fmaf(m0.y, m0.y, s0.y), m0.y*m0.z, m0.y*m0.w);
    A3 = make_float4(fmaf(m0.z, m0.z, s0.z), m0.z*m0.w,
                     fmaf(m0.w, m0.w, s0.w), 0.0f);
  }

  // preload obs row 1 (step t uses row t+1)
  float4 zz  = *(const float4*)&xhat[(size_t)(NB + n)*4];
  float4 sgc = *(const float4*)&sigma[(size_t)(NB + n)*4];

#pragma unroll 2
  for (int t = 0; t < T; ++t) {
    int nr = (t + 2 <= TP1 - 1) ? (t + 2) : (TP1 - 1);
    float4 zn  = *(const float4*)&xhat[((size_t)nr*NB + n)*4];
    float4 sgn = *(const float4*)&sigma[((size_t)nr*NB + n)*4];

    // ---- distributed predict from raw moments ----
    float rW = __fdividef(1.0f, A0.x);
    float dotq =
        ((fmaf(wp0, A1.y, wp1*A1.z) + fmaf(wp2, A1.w, wp3*A2.x)) +
         (fmaf(wp4, A2.y, wp5*A2.z) + fmaf(wp6, A2.w, wp7*A3.x))) +
        fmaf(wp8, A3.y, wp9*A3.z);
    float wdr = fmaf(ar0, A0.y, ar1*A0.z) + fmaf(ar2, A0.w, ar3*A1.x);
    float wdc = fmaf(ac0, A0.y, ac1*A0.z) + fmaf(ac2, A0.w, ac3*A1.x);
    float Amur = wdr * rW, Amuc = wdc * rW;
    float pe = fmaf(dotq, rW, initv);
    pe = fmaf(pmask, Amur, pe);
    pe = fmaf(-qmask, Amur*Amuc, pe);

    float p00 = rdlane(pe, 0), p01 = rdlane(pe, 1), p02 = rdlane(pe, 2), p03 = rdlane(pe, 3);
    float p11 = rdlane(pe, 4), p12 = rdlane(pe, 5), p13 = rdlane(pe, 6);
    float p22 = rdlane(pe, 7), p23 = rdlane(pe, 8), p33 = rdlane(pe, 9);
    float mp0 = rdlane(pe,10), mp1 = rdlane(pe,11), mp2 = rdlane(pe,12), mp3 = rdlane(pe,13);

    // ---- per-lane: S = Pp + diag(sigma); un-normalized adjugate ----
    float s00 = p00 + sgc.x, s11 = p11 + sgc.y, s22 = p22 + sgc.z, s33 = p33 + sgc.w;
    float s01 = p01, s02 = p02, s03 = p03, s12 = p12, s13 = p13, s23 = p23;

    float m0_ = s00*s11 - s01*s01;
    float m1_ = s00*s12 - s01*s02;
    float m2_ = s00*s13 - s01*s03;
    float m3_ = s01*s12 - s11*s02;
    float m4_ = s01*s13 - s11*s03;
    float m5_ = s02*s13 - s12*s03;
    float n5_ = s22*s33 - s23*s23;
    float n4_ = s12*s33 - s13*s23;
    float n3_ = s12*s23 - s13*s22;
    float n2_ = s02*s33 - s03*s23;
    float n1_ = s02*s23 - s03*s22;
    float det = (fmaf(m0_, n5_, -(m1_*n4_)) + fmaf(m2_, n3_, m3_*n2_)) +
                fmaf(m5_, m5_, -(m4_*n1_));
    float rsd = __builtin_amdgcn_rsqf(det);   // det^(-1/2), SPD => det > 0
    float id  = rsd * rsd;                    // 1/det
    float a00_ = ( s11*n5_ - s12*n4_ + s13*n3_);
    float a01_ = (-s01*n5_ + s02*n4_ - s03*n3_);
    float a02_ = ( s13*m5_ - s23*m4_ + s33*m3_);
    float a03_ = (-s12*m5_ + s22*m4_ - s23*m3_);
    float a11_ = ( s00*n5_ - s02*n2_ + s03*n1_);
    float a12_ = (-s03*m5_ + s23*m2_ - s33*m1_);
    float a13_ = ( s02*m5_ - s22*m2_ + s23*m1_);
    float a22_ = ( s03*m4_ - s13*m2_ + s33*m0_);
    float a23_ = (-s02*m4_ + s12*m2_ - s23*m0_);
    float a33_ = ( s02*m3_ - s12*m1_ + s22*m0_);

    float iv0 = zz.x - mp0, iv1 = zz.y - mp1, iv2 = zz.z - mp2, iv3 = zz.w - mp3;
    float ya0 = fmaf(a00_, iv0, a01_*iv1) + fmaf(a02_, iv2, a03_*iv3);
    float ya1 = fmaf(a01_, iv0, a11_*iv1) + fmaf(a12_, iv2, a13_*iv3);
    float ya2 = fmaf(a02_, iv0, a12_*iv1) + fmaf(a22_, iv2, a23_*iv3);
    float ya3 = fmaf(a03_, iv0, a13_*iv1) + fmaf(a23_, iv2, a33_*iv3);
    float quad = (fmaf(iv0, ya0, iv1*ya1) + fmaf(iv2, ya2, iv3*ya3)) * id;

    // softmax weight up to a wave-constant factor (cancels in normalize)
    float wi = __expf(-0.5f * quad) * rsd;

    // diagonal-R identity: mi = z − σ∘y  (y = S⁻¹ iv = ya·id)
    float y0 = ya0*id, y1 = ya1*id, y2 = ya2*id, y3 = ya3*id;
    float mi0 = fmaf(-sgc.x, y0, zz.x);
    float mi1 = fmaf(-sgc.y, y1, zz.y);
    float mi2 = fmaf(-sgc.z, y2, zz.z);
    float mi3 = fmaf(-sgc.w, y3, zz.w);

    const int par = t & 1;
    float* lb = xch[par];

    if (wv == 0) {
      float cW  = wsum_v(wi);
      float cm0 = wsum_v(wi*mi0);
      if (n == 63) { *(float2*)&lb[0] = make_float2(cW, cm0); }
    } else if (wv == 1) {
      float cm1 = wsum_v(wi*mi1);
      float cm2 = wsum_v(wi*mi2);
      if (n == 63) { *(float2*)&lb[2] = make_float2(cm1, cm2); }
    } else if (wv == 2) {
      float cm3 = wsum_v(wi*mi3);
      float t0 = sgc.x * id;
      float X00 = fmaf(mi0, mi0, sgc.x) - (t0*sgc.x)*a00_;
      float c00 = wsum_v(wi*X00);
      if (n == 63) { *(float2*)&lb[4] = make_float2(cm3, c00); }
    } else if (wv == 3) {
      float t0 = sgc.x * id;
      float X01 = fmaf(mi0, mi1, -(t0*sgc.y)*a01_);
      float X02 = fmaf(mi0, mi2, -(t0*sgc.z)*a02_);
      float c01 = wsum_v(wi*X01);
      float c02 = wsum_v(wi*X02);
      if (n == 63) { *(float2*)&lb[6] = make_float2(c01, c02); }
    } else if (wv == 4) {
      float t0 = sgc.x * id;
      float t1 = sgc.y * id;
      float X03 = fmaf(mi0, mi3, -(t0*sgc.w)*a03_);
      float X11 = fmaf(mi1, mi1, sgc.y) - (t1*sgc.y)*a11_;
      float c03 = wsum_v(wi*X03);
      float c11 = wsum_v(wi*X11);
      if (n == 63) { *(float2*)&lb[8] = make_float2(c03, c11); }
    } else if (wv == 5) {
      float t1 = sgc.y * id;
      float X12 = fmaf(mi1, mi2, -(t1*sgc.z)*a12_);
      float X13 = fmaf(mi1, mi3, -(t1*sgc.w)*a13_);
      float c12 = wsum_v(wi*X12);
      float c13 = wsum_v(wi*X13);
      if (n == 63) { *(float2*)&lb[10] = make_float2(c12, c13); }
    } else if (wv == 6) {
      float t2 = sgc.z * id;
      float X22 = fmaf(mi2, mi2, sgc.z) - (t2*sgc.z)*a22_;
      float X23 = fmaf(mi2, mi3, -(t2*sgc.w)*a23_);
      float c22 = wsum_v(wi*X22);
      float c23 = wsum_v(wi*X23);
      if (n == 63) { *(float2*)&lb[12] = make_float2(c22, c23); }
    } else {
      float t3 = sgc.w * id;
      float X33 = fmaf(mi3, mi3, sgc.w) - (t3*sgc.w)*a33_;
      float c33 = wsum_v(wi*X33);
      if (n == 63) { lb[14] = c33; }
    }

    __syncthreads();

    A0 = *(const float4*)&xch[par][0];
    A1 = *(const float4*)&xch[par][4];
    A2 = *(const float4*)&xch[par][8];
    A3 = *(const float4*)&xch[par][12];

    if (wv == 0 && n == 0) {
      float* fp = &fr[((size_t)t*NB + fi)*16];
      *(float4*)&fp[0]  = A0;
      *(float4*)&fp[4]  = A1;
      *(float4*)&fp[8]  = A2;
      *(float4*)&fp[12] = A3;
    }
    zz = zn; sgc = sgn;
  }
}

// ==========================================================================
// Backward smoother as an affine suffix scan (unchanged from round 9)
// ==========================================================================
struct Map { float G[4][4]; float c[4]; float Dm[4][4]; };

__device__ __forceinline__ void map_identity(Map& M) {
#pragma unroll
  for (int r = 0; r < 4; ++r) {
    M.c[r] = 0.f;
#pragma unroll
    for (int cc = 0; cc < 4; ++cc) { M.G[r][cc] = (r==cc)?1.f:0.f; M.Dm[r][cc] = 0.f; }
  }
}

// R = F ∘ S (apply S first, then F); R may alias either arg
__device__ __forceinline__ void compose(const Map& F, const Map& Sm, Map& R) {
  float G[4][4], cv[4], V[4][4], Dn[4][4];
#pragma unroll
  for (int r = 0; r < 4; ++r)
#pragma unroll
    for (int c = 0; c < 4; ++c)
      G[r][c] = F.G[r][0]*Sm.G[0][c] + F.G[r][1]*Sm.G[1][c]
              + F.G[r][2]*Sm.G[2][c] + F.G[r][3]*Sm.G[3][c];
#pragma unroll
  for (int r = 0; r < 4; ++r)
    cv[r] = F.c[r] + F.G[r][0]*Sm.c[0] + F.G[r][1]*Sm.c[1]
                   + F.G[r][2]*Sm.c[2] + F.G[r][3]*Sm.c[3];
#pragma unroll
  for (int r = 0; r < 4; ++r)
#pragma unroll
    for (int c = 0; c < 4; ++c)
      V[r][c] = F.G[r][0]*Sm.Dm[0][c] + F.G[r][1]*Sm.Dm[1][c]
              + F.G[r][2]*Sm.Dm[2][c] + F.G[r][3]*Sm.Dm[3][c];
#pragma unroll
  for (int r = 0; r < 4; ++r)
#pragma unroll
    for (int c = r; c < 4; ++c) {
      float v = F.Dm[r][c] + V[r][0]*F.G[c][0] + V[r][1]*F.G[c][1]
                           + V[r][2]*F.G[c][2] + V[r][3]*F.G[c][3];
      Dn[r][c] = v; Dn[c][r] = v;
    }
#pragma unroll
  for (int r = 0; r < 4; ++r) {
    R.c[r] = cv[r];
#pragma unroll
    for (int c = 0; c < 4; ++c) { R.G[r][c] = G[r][c]; R.Dm[r][c] = Dn[r][c]; }
  }
}

// per-step map f_t for filter i (from raw forward results)
__device__ __forceinline__ void make_ft(int t, int i,
    const float* __restrict__ fr,
    const float A[4][4], const float b[4], const float Q[4][4], Map& M) {
  float mf[4], Pf[4][4];
  load_state_raw(&fr[((size_t)t*NB + i)*16], mf, Pf);
  float mp[4];
#pragma unroll
  for (int r = 0; r < 4; ++r)
    mp[r] = b[r] + A[r][0]*mf[0] + A[r][1]*mf[1] + A[r][2]*mf[2] + A[r][3]*mf[3];
  float AP[4][4];
#pragma unroll
  for (int r = 0; r < 4; ++r)
#pragma unroll
    for (int c = 0; c < 4; ++c)
      AP[r][c] = A[r][0]*Pf[0][c] + A[r][1]*Pf[1][c] + A[r][2]*Pf[2][c] + A[r][3]*Pf[3][c];
  float Pp[4][4];
#pragma unroll
  for (int r = 0; r < 4; ++r)
#pragma unroll
    for (int c = r; c < 4; ++c) {
      float v = Q[r][c] + AP[r][0]*A[c][0] + AP[r][1]*A[c][1]
                        + AP[r][2]*A[c][2] + AP[r][3]*A[c][3];
      Pp[r][c] = v; Pp[c][r] = v;
    }
  float Ppi[4][4];
  inv4(Pp, Ppi);
  float W[4][4]; // Pf A^T
#pragma unroll
  for (int r = 0; r < 4; ++r)
#pragma unroll
    for (int c = 0; c < 4; ++c)
      W[r][c] = Pf[r][0]*A[c][0] + Pf[r][1]*A[c][1] + Pf[r][2]*A[c][2] + Pf[r][3]*A[c][3];
#pragma unroll
  for (int r = 0; r < 4; ++r)
#pragma unroll
    for (int c = 0; c < 4; ++c)
      M.G[r][c] = W[r][0]*Ppi[0][c] + W[r][1]*Ppi[1][c] + W[r][2]*Ppi[2][c] + W[r][3]*Ppi[3][c];
#pragma unroll
  for (int r = 0; r < 4; ++r)
    M.c[r] = mf[r] - (M.G[r][0]*mp[0] + M.G[r][1]*mp[1] + M.G[r][2]*mp[2] + M.G[r][3]*mp[3]);
  float V[4][4];
#pragma unroll
  for (int r = 0; r < 4; ++r)
#pragma unroll
    for (int c = 0; c < 4; ++c)
      V[r][c] = M.G[r][0]*Pp[0][c] + M.G[r][1]*Pp[1][c] + M.G[r][2]*Pp[2][c] + M.G[r][3]*Pp[3][c];
#pragma unroll
  for (int r = 0; r < 4; ++r)
#pragma unroll
    for (int c = r; c < 4; ++c) {
      float v = Pf[r][c] - (V[r][0]*M.G[c][0] + V[r][1]*M.G[c][1]
                          + V[r][2]*M.G[c][2] + V[r][3]*M.G[c][3]);
      M.Dm[r][c] = v; M.Dm[c][r] = v;
    }
}

__device__ __forceinline__ void store_map(float* __restrict__ p, const Map& M) {
  *(float4*)&p[0]  = make_float4(M.G[0][0],M.G[0][1],M.G[0][2],M.G[0][3]);
  *(float4*)&p[4]  = make_float4(M.G[1][0],M.G[1][1],M.G[1][2],M.G[1][3]);
  *(float4*)&p[8]  = make_float4(M.G[2][0],M.G[2][1],M.G[2][2],M.G[2][3]);
  *(float4*)&p[12] = make_float4(M.G[3][0],M.G[3][1],M.G[3][2],M.G[3][3]);
  *(float4*)&p[16] = make_float4(M.c[0],M.c[1],M.c[2],M.c[3]);
  *(float4*)&p[20] = make_float4(M.Dm[0][0],M.Dm[0][1],M.Dm[0][2],M.Dm[0][3]);
  *(float4*)&p[24] = make_float4(M.Dm[1][0],M.Dm[1][1],M.Dm[1][2],M.Dm[1][3]);
  *(float4*)&p[28] = make_float4(M.Dm[2][0],M.Dm[2][1],M.Dm[2][2],M.Dm[2][3]);
  *(float4*)&p[32] = make_float4(M.Dm[3][0],M.Dm[3][1],M.Dm[3][2],M.Dm[3][3]);
}
__device__ __forceinline__ void load_map(const float* __restrict__ p, Map& M) {
  float4 g0=*(const float4*)&p[0], g1=*(const float4*)&p[4],
         g2=*(const float4*)&p[8], g3=*(const float4*)&p[12];
  float4 cv=*(const float4*)&p[16];
  float4 d0=*(const float4*)&p[20], d1=*(const float4*)&p[24],
         d2=*(const float4*)&p[28], d3=*(const float4*)&p[32];
  M.G[0][0]=g0.x;M.G[0][1]=g0.y;M.G[0][2]=g0.z;M.G[0][3]=g0.w;
  M.G[1][0]=g1.x;M.G[1][1]=g1.y;M.G[1][2]=g1.z;M.G[1][3]=g1.w;
  M.G[2][0]=g2.x;M.G[2][1]=g2.y;M.G[2][2]=g2.z;M.G[2][3]=g2.w;
  M.G[3][0]=g3.x;M.G[3][1]=g3.y;M.G[3][2]=g3.z;M.G[3][3]=g3.w;
  M.c[0]=cv.x;M.c[1]=cv.y;M.c[2]=cv.z;M.c[3]=cv.w;
  M.Dm[0][0]=d0.x;M.Dm[0][1]=d0.y;M.Dm[0][2]=d0.z;M.Dm[0][3]=d0.w;
  M.Dm[1][0]=d1.x;M.Dm[1][1]=d1.y;M.Dm[1][2]=d1.z;M.Dm[1][3]=d1.w;
  M.Dm[2][0]=d2.x;M.Dm[2][1]=d2.y;M.Dm[2][2]=d2.z;M.Dm[2][3]=d2.w;
  M.Dm[3][0]=d3.x;M.Dm[3][1]=d3.y;M.Dm[3][2]=d3.z;M.Dm[3][3]=d3.w;
}

// LDS map I/O, stride-37 floats (bank-conflict-free scalar layout)
__device__ __forceinline__ void store_map_lds(float* p, const Map& M) {
#pragma unroll
  for (int r = 0; r < 4; ++r) {
#pragma unroll
    for (int c2 = 0; c2 < 4; ++c2) {
      p[r*4+c2]    = M.G[r][c2];
      p[20+r*4+c2] = M.Dm[r][c2];
    }
    p[16+r] = M.c[r];
  }
}
__device__ __forceinline__ void load_map_lds(const float* p, Map& M) {
#pragma unroll
  for (int r = 0; r < 4; ++r) {
#pragma unroll
    for (int c2 = 0; c2 < 4; ++c2) {
      M.G[r][c2]  = p[r*4+c2];
      M.Dm[r][c2] = p[20+r*4+c2];
    }
    M.c[r] = p[16+r];
  }
}

// K3 phase A: per (chunk, filter) compose chunk aggregate right-to-left
__global__ void __launch_bounds__(64, 1) k_phaseA(
    const float* __restrict__ fr,
    const float* __restrict__ Ag, const float* __restrict__ bg,
    const float* __restrict__ qp, float* __restrict__ Cw) {
  const int cc = blockIdx.x;
  const int i  = threadIdx.x;
  float A[4][4], Q[4][4], b[4];
  load_A_b_Q(Ag, bg, qp, A, b, Q);
  Map agg; map_identity(agg);
  int a = cc * CLEN;
  int bb = a + CLEN - 1; if (bb > T - 2) bb = T - 2;
  for (int t = bb; t >= a; --t) {
    Map f; make_ft(t, i, fr, A, b, Q, f);
    compose(f, agg, agg);
  }
  store_map(&Cw[((size_t)i*CH + cc)*36], agg);
}

// K4 phase B: per filter, parallel Hillis-Steele suffix scan over CH chunks
__global__ void __launch_bounds__(CH, 1) k_phaseB(
    const float* __restrict__ Cw, float* __restrict__ Ew) {
  const int fi = blockIdx.x;
  const int cc = threadIdx.x;
  __shared__ float lds[CH * 37];

  Map M;
  load_map(&Cw[((size_t)fi*CH + cc)*36], M);
  store_map_lds(&lds[cc*37], M);
  __syncthreads();

#pragma unroll
  for (int k = 0; k < 8; ++k) {        // log2(CH) = 8
    int step = 1 << k;
    Map P;
    bool have = (cc + step < CH);
    if (have) load_map_lds(&lds[(cc+step)*37], P);
    __syncthreads();
    if (have) {
      compose(M, P, M);                // M spans [cc, cc+2^{k+1})
      store_map_lds(&lds[cc*37], M);
    }
    __syncthreads();
  }

  Map E;
  if (cc == CH - 1) map_identity(E);
  else              load_map_lds(&lds[(cc+1)*37], E);
  store_map(&Ew[((size_t)fi*CH + cc)*36], E);
}

// cholesky of sP+1e-5 I, z = sm + L eps, out = z @ dec_w + dec_b
__device__ __forceinline__ void recon(int t, int i,
    const float sm[4], const float sP[4][4],
    const float* __restrict__ eps, const float* __restrict__ dw,
    const float* __restrict__ db, float* __restrict__ out) {
  float a00 = sP[0][0]+1e-5f, a11 = sP[1][1]+1e-5f, a22 = sP[2][2]+1e-5f, a33 = sP[3][3]+1e-5f;
  float L00 = sqrtf(a00);
  float r0 = __fdividef(1.0f, L00);
  float L10 = sP[1][0]*r0, L20 = sP[2][0]*r0, L30 = sP[3][0]*r0;
  float L11 = sqrtf(a11 - L10*L10);
  float r1 = __fdividef(1.0f, L11);
  float L21 = (sP[2][1]-L20*L10)*r1, L31 = (sP[3][1]-L30*L10)*r1;
  float L22 = sqrtf(a22 - L20*L20 - L21*L21);
  float r2 = __fdividef(1.0f, L22);
  float L32 = (sP[3][2]-L30*L20-L31*L21)*r2;
  float L33 = sqrtf(a33 - L30*L30 - L31*L31 - L32*L32);
  float4 e = *(const float4*)&eps[((size_t)t*NB + i)*4];
  float z0 = sm[0] + L00*e.x;
  float z1 = sm[1] + L10*e.x + L11*e.y;
  float z2 = sm[2] + L20*e.x + L21*e.y + L22*e.z;
  float z3 = sm[3] + L30*e.x + L31*e.y + L32*e.z + L33*e.w;
#pragma unroll
  for (int p = 0; p < 3; ++p)
    out[((size_t)t*NB + i)*3 + p] =
        db[p] + z0*dw[0*3+p] + z1*dw[1*3+p] + z2*dw[2*3+p] + z3*dw[3*3+p];
}

// K5 phase C: apply exclusive suffix, walk chunk downward emitting recon
__global__ void __launch_bounds__(64, 1) k_phaseC(
    const float* __restrict__ fr,
    const float* __restrict__ Ew,
    const float* __restrict__ Ag, const float* __restrict__ bg,
    const float* __restrict__ qp,
    const float* __restrict__ eps, const float* __restrict__ dw,
    const float* __restrict__ db, float* __restrict__ out) {
  const int cc = blockIdx.x;
  const int i  = threadIdx.x;
  float A[4][4], Q[4][4], b[4];
  load_A_b_Q(Ag, bg, qp, A, b, Q);

  // final filtered state (t = T-1) == final smoothed state
  float mT[4], PT[4][4];
  load_state_raw(&fr[((size_t)(T-1)*NB + i)*16], mT, PT);

  Map E; load_map(&Ew[((size_t)i*CH + cc)*36], E);

  float sm[4], sP[4][4];
#pragma unroll
  for (int r = 0; r < 4; ++r)
    sm[r] = E.c[r] + E.G[r][0]*mT[0] + E.G[r][1]*mT[1] + E.G[r][2]*mT[2] + E.G[r][3]*mT[3];
  {
    float V[4][4];
#pragma unroll
    for (int r = 0; r < 4; ++r)
#pragma unroll
      for (int c = 0; c < 4; ++c)
        V[r][c] = E.G[r][0]*PT[0][c] + E.G[r][1]*PT[1][c] + E.G[r][2]*PT[2][c] + E.G[r][3]*PT[3][c];
#pragma unroll
    for (int r = 0; r < 4; ++r)
#pragma unroll
      for (int c = r; c < 4; ++c) {
        float v = E.Dm[r][c] + V[r][0]*E.G[c][0] + V[r][1]*E.G[c][1]
                             + V[r][2]*E.G[c][2] + V[r][3]*E.G[c][3];
        sP[r][c] = v; sP[c][r] = v;
      }
  }

  if (cc == CH - 1) recon(T - 1, i, mT, PT, eps, dw, db, out);

  int a = cc * CLEN;
  int bb = a + CLEN - 1; if (bb > T - 2) bb = T - 2;
  for (int t = bb; t >= a; --t) {
    Map f; make_ft(t, i, fr, A, b, Q, f);
    float smn[4];
#pragma unroll
    for (int r = 0; r < 4; ++r)
      smn[r] = f.c[r] + f.G[r][0]*sm[0] + f.G[r][1]*sm[1] + f.G[r][2]*sm[2] + f.G[r][3]*sm[3];
    float V[4][4];
#pragma unroll
    for (int r = 0; r < 4; ++r)
#pragma unroll
      for (int c = 0; c < 4; ++c)
        V[r][c] = f.G[r][0]*sP[0][c] + f.G[r][1]*sP[1][c] + f.G[r][2]*sP[2][c] + f.G[r][3]*sP[3][c];
#pragma unroll
    for (int r = 0; r < 4; ++r)
#pragma unroll
      for (int c = r; c < 4; ++c) {
        float v = f.Dm[r][c] + V[r][0]*f.G[c][0] + V[r][1]*f.G[c][1]
                             + V[r][2]*f.G[c][2] + V[r][3]*f.G[c][3];
        sP[r][c] = v; sP[c][r] = v;
      }
    sm[0]=smn[0]; sm[1]=smn[1]; sm[2]=smn[2]; sm[3]=smn[3];
    recon(t, i, sm, sP, eps, dw, db, out);
  }
}

// ==========================================================================
extern "C" void kernel_launch(void* const* d_in, const int* in_sizes, int n_in,
                              void* d_out, int out_size, void* d_ws, size_t ws_size,
                              hipStream_t stream) {
  const float* x   = (const float*)d_in[0];
  const float* eps = (const float*)d_in[1];
  const float* w1  = (const float*)d_in[2];
  const float* b1  = (const float*)d_in[3];
  const float* wx  = (const float*)d_in[4];
  const float* bx  = (const float*)d_in[5];
  const float* wl  = (const float*)d_in[6];
  const float* bl  = (const float*)d_in[7];
  const float* dw  = (const float*)d_in[8];
  const float* db  = (const float*)d_in[9];
  const float* Ag  = (const float*)d_in[10];
  const float* bg  = (const float*)d_in[11];
  const float* qp  = (const float*)d_in[12];

  float* ws    = (float*)d_ws;
  float* xhat  = ws + OFF_XHAT;
  float* sigma = ws + OFF_SIGMA;
  float* fr    = ws + OFF_FR;
  float* Cw    = ws + OFF_C;
  float* Ew    = ws + OFF_E;
  float* out   = (float*)d_out;

  k_encoder<<<(TP1*NB + 255)/256, 256, 0, stream>>>(x, w1, b1, wx, bx, wl, bl, xhat, sigma);
  k_filter<<<NB, 512, 0, stream>>>(xhat, sigma, Ag, bg, qp, fr);
  k_phaseA<<<CH, NB, 0, stream>>>(fr, Ag, bg, qp, Cw);
  k_phaseB<<<NB, CH, 0, stream>>>(Cw, Ew);
  k_phaseC<<<CH, NB, 0, stream>>>(fr, Ew, Ag, bg, qp, eps, dw, db, out);
}

// Round 12
// 1571.671 us; speedup vs baseline: 2.4749x; 1.3977x over previous
//
#include <hip/hip_runtime.h>
#include <math.h>

#define D4   4
#define NB   64      // batch = #filters = #observations
#define T    2048
#define TP1  2049
#define HID  20
#define POS  3
#define CH   256     // chunks for backward parallel scan
#define CLEN 8       // chunk length (CH*CLEN >= T-1)

// ---- workspace layout (floats) -------------------------------------------
#define OFF_XHAT  0
#define OFF_SIGMA (TP1*NB*4)
#define OFF_FR    (2*TP1*NB*4)
#define OFF_C     (OFF_FR + T*NB*16)
#define OFF_E     (OFF_C + NB*CH*36)

// ---- DPP wave reductions (VALU pipe, no LDS) ------------------------------
template<int CTRL, int RM>
__device__ __forceinline__ float dpp_sum_step(float v) {
  int t = __builtin_amdgcn_update_dpp(0, __float_as_int(v), CTRL, RM, 0xF, true);
  return v + __int_as_float(t);
}
// sum across 64 lanes; TOTAL lands in lane 63 (no broadcast)
__device__ __forceinline__ float wsum_v(float v) {
  v = dpp_sum_step<0x111, 0xF>(v);   // row_shr:1
  v = dpp_sum_step<0x112, 0xF>(v);   // row_shr:2
  v = dpp_sum_step<0x114, 0xF>(v);   // row_shr:4
  v = dpp_sum_step<0x118, 0xF>(v);   // row_shr:8
  v = dpp_sum_step<0x142, 0xA>(v);   // row_bcast:15 into rows 1,3
  v = dpp_sum_step<0x143, 0xC>(v);   // row_bcast:31 into rows 2,3
  return v;
}
__device__ __forceinline__ float rdlane(float v, int l) {
  return __int_as_float(__builtin_amdgcn_readlane(__float_as_int(v), l));
}

// ---- 4x4 inverse (adjugate, general); returns det ------------------------
__device__ __forceinline__ float inv4(const float a[4][4], float inv[4][4]) {
  float s0 = a[0][0]*a[1][1] - a[1][0]*a[0][1];
  float s1 = a[0][0]*a[1][2] - a[1][0]*a[0][2];
  float s2 = a[0][0]*a[1][3] - a[1][0]*a[0][3];
  float s3 = a[0][1]*a[1][2] - a[1][1]*a[0][2];
  float s4 = a[0][1]*a[1][3] - a[1][1]*a[0][3];
  float s5 = a[0][2]*a[1][3] - a[1][2]*a[0][3];
  float c5 = a[2][2]*a[3][3] - a[3][2]*a[2][3];
  float c4 = a[2][1]*a[3][3] - a[3][1]*a[2][3];
  float c3 = a[2][1]*a[3][2] - a[3][1]*a[2][2];
  float c2 = a[2][0]*a[3][3] - a[3][0]*a[2][3];
  float c1 = a[2][0]*a[3][2] - a[3][0]*a[2][2];
  float c0 = a[2][0]*a[3][1] - a[3][0]*a[2][1];
  float det = s0*c5 - s1*c4 + s2*c3 + s3*c2 - s4*c1 + s5*c0;
  float id = __fdividef(1.0f, det);
  inv[0][0] = ( a[1][1]*c5 - a[1][2]*c4 + a[1][3]*c3) * id;
  inv[0][1] = (-a[0][1]*c5 + a[0][2]*c4 - a[0][3]*c3) * id;
  inv[0][2] = ( a[3][1]*s5 - a[3][2]*s4 + a[3][3]*s3) * id;
  inv[0][3] = (-a[2][1]*s5 + a[2][2]*s4 - a[2][3]*s3) * id;
  inv[1][0] = (-a[1][0]*c5 + a[1][2]*c2 - a[1][3]*c1) * id;
  inv[1][1] = ( a[0][0]*c5 - a[0][2]*c2 + a[0][3]*c1) * id;
  inv[1][2] = (-a[3][0]*s5 + a[3][2]*s2 - a[3][3]*s1) * id;
  inv[1][3] = ( a[2][0]*s5 - a[2][2]*s2 + a[2][3]*s1) * id;
  inv[2][0] = ( a[1][0]*c4 - a[1][1]*c2 + a[1][3]*c0) * id;
  inv[2][1] = (-a[0][0]*c4 + a[0][1]*c2 - a[0][3]*c0) * id;
  inv[2][2] = ( a[3][0]*s4 - a[3][1]*s2 + a[3][3]*s0) * id;
  inv[2][3] = (-a[2][0]*s4 + a[2][1]*s2 - a[2][3]*s0) * id;
  inv[3][0] = (-a[1][0]*c3 + a[1][1]*c1 - a[1][2]*c0) * id;
  inv[3][1] = ( a[0][0]*c3 - a[0][1]*c1 + a[0][2]*c0) * id;
  inv[3][2] = (-a[3][0]*s3 + a[3][1]*s1 - a[3][2]*s0) * id;
  inv[3][3] = ( a[2][0]*s3 - a[2][1]*s1 + a[2][2]*s0) * id;
  return det;
}

// ---- Q = L L^T from q_param (tril_indices row-major order) ---------------
__device__ __forceinline__ void build_Q(const float* __restrict__ qp, float Q[4][4]) {
  float L[4][4] = {{0.f,0.f,0.f,0.f},{0.f,0.f,0.f,0.f},{0.f,0.f,0.f,0.f},{0.f,0.f,0.f,0.f}};
  L[0][0] = expf(qp[0]);
  L[1][0] = qp[1]; L[1][1] = expf(qp[2]);
  L[2][0] = qp[3]; L[2][1] = qp[4]; L[2][2] = expf(qp[5]);
  L[3][0] = qp[6]; L[3][1] = qp[7]; L[3][2] = qp[8]; L[3][3] = expf(qp[9]);
#pragma unroll
  for (int r = 0; r < 4; ++r)
#pragma unroll
    for (int c = 0; c < 4; ++c) {
      float v = 0.f;
#pragma unroll
      for (int k = 0; k < 4; ++k) v += L[r][k] * L[c][k];
      Q[r][c] = v;
    }
}

__device__ __forceinline__ void load_A_b_Q(const float* __restrict__ Ag,
                                           const float* __restrict__ bg,
                                           const float* __restrict__ qp,
                                           float A[4][4], float b[4], float Q[4][4]) {
#pragma unroll
  for (int r = 0; r < 4; ++r) {
    b[r] = bg[r];
#pragma unroll
    for (int c = 0; c < 4; ++c) A[r][c] = Ag[r * 4 + c];
  }
  build_Q(qp, Q);
}

// reconstruct filtered (mf, Pf) from raw moments {W, wm, q}
__device__ __forceinline__ void load_state_raw(const float* __restrict__ p,
                                               float mf[4], float Pf[4][4]) {
  float4 r0 = *(const float4*)&p[0];
  float4 r1 = *(const float4*)&p[4];
  float4 r2 = *(const float4*)&p[8];
  float4 r3 = *(const float4*)&p[12];
  float rW = __fdividef(1.0f, r0.x);
  mf[0]=r0.y*rW; mf[1]=r0.z*rW; mf[2]=r0.w*rW; mf[3]=r1.x*rW;
  Pf[0][0]=fmaf(r1.y,rW,-mf[0]*mf[0]);
  Pf[0][1]=fmaf(r1.z,rW,-mf[0]*mf[1]); Pf[1][0]=Pf[0][1];
  Pf[0][2]=fmaf(r1.w,rW,-mf[0]*mf[2]); Pf[2][0]=Pf[0][2];
  Pf[0][3]=fmaf(r2.x,rW,-mf[0]*mf[3]); Pf[3][0]=Pf[0][3];
  Pf[1][1]=fmaf(r2.y,rW,-mf[1]*mf[1]);
  Pf[1][2]=fmaf(r2.z,rW,-mf[1]*mf[2]); Pf[2][1]=Pf[1][2];
  Pf[1][3]=fmaf(r2.w,rW,-mf[1]*mf[3]); Pf[3][1]=Pf[1][3];
  Pf[2][2]=fmaf(r3.x,rW,-mf[2]*mf[2]);
  Pf[2][3]=fmaf(r3.y,rW,-mf[2]*mf[3]); Pf[3][2]=Pf[2][3];
  Pf[3][3]=fmaf(r3.z,rW,-mf[3]*mf[3]);
}

// ==========================================================================
// K1: encoder
// ==========================================================================
__global__ void k_encoder(const float* __restrict__ x,
                          const float* __restrict__ w1, const float* __restrict__ b1,
                          const float* __restrict__ wx, const float* __restrict__ bx,
                          const float* __restrict__ wl, const float* __restrict__ bl,
                          float* __restrict__ xhat, float* __restrict__ sigma) {
  int idx = blockIdx.x * blockDim.x + threadIdx.x;
  if (idx >= TP1 * NB) return;
  float x0 = x[idx*3+0], x1 = x[idx*3+1], x2 = x[idx*3+2];
  float xh[4], lm[4];
#pragma unroll
  for (int k = 0; k < 4; ++k) { xh[k] = bx[k]; lm[k] = bl[k]; }
#pragma unroll
  for (int j = 0; j < HID; ++j) {
    float h = x0*w1[0*HID+j] + x1*w1[1*HID+j] + x2*w1[2*HID+j] + b1[j];
    h = fmaxf(h, 0.0f);
#pragma unroll
    for (int k = 0; k < 4; ++k) { xh[k] += h * wx[j*4+k]; lm[k] += h * wl[j*4+k]; }
  }
  *(float4*)&xhat[(size_t)idx*4]  = make_float4(xh[0], xh[1], xh[2], xh[3]);
  *(float4*)&sigma[(size_t)idx*4] = make_float4(expf(0.5f*lm[0]), expf(0.5f*lm[1]),
                                                expf(0.5f*lm[2]), expf(0.5f*lm[3]));
}

// ==========================================================================
// K2: forward mixture Kalman filter — 4 waves per filter (256-thread block)
//   (round-9 configuration — best measured: 1468 µs)
// ==========================================================================
__global__ void __launch_bounds__(256, 1) k_filter(
    const float* __restrict__ xhat, const float* __restrict__ sigma,
    const float* __restrict__ Ag, const float* __restrict__ bg,
    const float* __restrict__ qp,
    float* __restrict__ fr) {
  const int fi  = blockIdx.x;        // filter
  const int tid = threadIdx.x;
  const int wv  = tid >> 6;          // wave id (0..3)
  const int n   = tid & 63;          // observation lane

  __shared__ __align__(16) float xch[2][16];

  // ---- per-lane predict-entry setup (once) ----
  int r, c;
  if (n < 10) {
    r = (n < 4) ? 0 : (n < 7) ? 1 : (n < 9) ? 2 : 3;
    c = (n < 4) ? n : (n < 7) ? n - 3 : (n < 9) ? n - 5 : 3;
  } else if (n < 14) { r = n - 10; c = 0; }
  else { r = 0; c = 0; }

  float ar0 = Ag[r*4+0], ar1 = Ag[r*4+1], ar2 = Ag[r*4+2], ar3 = Ag[r*4+3];
  float ac0 = Ag[c*4+0], ac1 = Ag[c*4+1], ac2 = Ag[c*4+2], ac3 = Ag[c*4+3];
  float qmask = (n < 10) ? 1.0f : 0.0f;
  float pmask = (n >= 10 && n < 14) ? 1.0f : 0.0f;
  float wp0 = (ar0*ac0) * qmask;
  float wp1 = (ar0*ac1 + ar1*ac0) * qmask;
  float wp2 = (ar0*ac2 + ar2*ac0) * qmask;
  float wp3 = (ar0*ac3 + ar3*ac0) * qmask;
  float wp4 = (ar1*ac1) * qmask;
  float wp5 = (ar1*ac2 + ar2*ac1) * qmask;
  float wp6 = (ar1*ac3 + ar3*ac1) * qmask;
  float wp7 = (ar2*ac2) * qmask;
  float wp8 = (ar2*ac3 + ar3*ac2) * qmask;
  float wp9 = (ar3*ac3) * qmask;

  float initv;   // lanes<10: Q_e ; lanes 10-13: b_r ; else 0
  {
    int trir = r*(r+1)/2, tric = c*(c+1)/2;
    float Lr[4], Lc[4];
#pragma unroll
    for (int k = 0; k < 4; ++k) {
      Lr[k] = (k > r) ? 0.0f : (k == r ? expf(qp[trir+r]) : qp[trir+k]);
      Lc[k] = (k > c) ? 0.0f : (k == c ? expf(qp[tric+c]) : qp[tric+k]);
    }
    float Qe = Lr[0]*Lc[0] + Lr[1]*Lc[1] + Lr[2]*Lc[2] + Lr[3]*Lc[3];
    if (n < 10)      initv = Qe;
    else if (n < 14) initv = bg[n-10];
    else             initv = 0.0f;
  }

  // ---- seed raw state: W=1, wm=m0, q = P0 + m0 m0^T (P0 = diag(s0)) ----
  float4 A0, A1, A2, A3;
  {
    float4 m0 = *(const float4*)&xhat[fi*4];
    float4 s0 = *(const float4*)&sigma[fi*4];
    A0 = make_float4(1.0f, m0.x, m0.y, m0.z);
    A1 = make_float4(m0.w,
                     fmaf(m0.x, m0.x, s0.x), m0.x*m0.y, m0.x*m0.z);
    A2 = make_float4(m0.x*m0.w,
                     fmaf(m0.y, m0.y, s0.y), m0.y*m0.z, m0.y*m0.w);
    A3 = make_float4(fmaf(m0.z, m0.z, s0.z), m0.z*m0.w,
                     fmaf(m0.w, m0.w, s0.w), 0.0f);
  }

  // preload obs row 1 (step t uses row t+1)
  float4 zz  = *(const float4*)&xhat[(size_t)(NB + n)*4];
  float4 sgc = *(const float4*)&sigma[(size_t)(NB + n)*4];

#pragma unroll 2
  for (int t = 0; t < T; ++t) {
    int nr = (t + 2 <= TP1 - 1) ? (t + 2) : (TP1 - 1);
    float4 zn  = *(const float4*)&xhat[((size_t)nr*NB + n)*4];
    float4 sgn = *(const float4*)&sigma[((size_t)nr*NB + n)*4];

    // ---- distributed predict from raw moments ----
    float rW = __fdividef(1.0f, A0.x);
    float dotq =
        ((fmaf(wp0, A1.y, wp1*A1.z) + fmaf(wp2, A1.w, wp3*A2.x)) +
         (fmaf(wp4, A2.y, wp5*A2.z) + fmaf(wp6, A2.w, wp7*A3.x))) +
        fmaf(wp8, A3.y, wp9*A3.z);
    float wdr = fmaf(ar0, A0.y, ar1*A0.z) + fmaf(ar2, A0.w, ar3*A1.x);
    float wdc = fmaf(ac0, A0.y, ac1*A0.z) + fmaf(ac2, A0.w, ac3*A1.x);
    float Amur = wdr * rW, Amuc = wdc * rW;
    float pe = fmaf(dotq, rW, initv);
    pe = fmaf(pmask, Amur, pe);
    pe = fmaf(-qmask, Amur*Amuc, pe);

    float p00 = rdlane(pe, 0), p01 = rdlane(pe, 1), p02 = rdlane(pe, 2), p03 = rdlane(pe, 3);
    float p11 = rdlane(pe, 4), p12 = rdlane(pe, 5), p13 = rdlane(pe, 6);
    float p22 = rdlane(pe, 7), p23 = rdlane(pe, 8), p33 = rdlane(pe, 9);
    float mp0 = rdlane(pe,10), mp1 = rdlane(pe,11), mp2 = rdlane(pe,12), mp3 = rdlane(pe,13);

    // ---- per-lane: S = Pp + diag(sigma); un-normalized adjugate ----
    float s00 = p00 + sgc.x, s11 = p11 + sgc.y, s22 = p22 + sgc.z, s33 = p33 + sgc.w;
    float s01 = p01, s02 = p02, s03 = p03, s12 = p12, s13 = p13, s23 = p23;

    float m0_ = s00*s11 - s01*s01;
    float m1_ = s00*s12 - s01*s02;
    float m2_ = s00*s13 - s01*s03;
    float m3_ = s01*s12 - s11*s02;
    float m4_ = s01*s13 - s11*s03;
    float m5_ = s02*s13 - s12*s03;
    float n5_ = s22*s33 - s23*s23;
    float n4_ = s12*s33 - s13*s23;
    float n3_ = s12*s23 - s13*s22;
    float n2_ = s02*s33 - s03*s23;
    float n1_ = s02*s23 - s03*s22;
    float det = (fmaf(m0_, n5_, -(m1_*n4_)) + fmaf(m2_, n3_, m3_*n2_)) +
                fmaf(m5_, m5_, -(m4_*n1_));
    float rsd = __builtin_amdgcn_rsqf(det);   // det^(-1/2), SPD => det > 0
    float id  = rsd * rsd;                    // 1/det
    float a00_ = ( s11*n5_ - s12*n4_ + s13*n3_);
    float a01_ = (-s01*n5_ + s02*n4_ - s03*n3_);
    float a02_ = ( s13*m5_ - s23*m4_ + s33*m3_);
    float a03_ = (-s12*m5_ + s22*m4_ - s23*m3_);
    float a11_ = ( s00*n5_ - s02*n2_ + s03*n1_);
    float a12_ = (-s03*m5_ + s23*m2_ - s33*m1_);
    float a13_ = ( s02*m5_ - s22*m2_ + s23*m1_);
    float a22_ = ( s03*m4_ - s13*m2_ + s33*m0_);
    float a23_ = (-s02*m4_ + s12*m2_ - s23*m0_);
    float a33_ = ( s02*m3_ - s12*m1_ + s22*m0_);

    float iv0 = zz.x - mp0, iv1 = zz.y - mp1, iv2 = zz.z - mp2, iv3 = zz.w - mp3;
    float ya0 = fmaf(a00_, iv0, a01_*iv1) + fmaf(a02_, iv2, a03_*iv3);
    float ya1 = fmaf(a01_, iv0, a11_*iv1) + fmaf(a12_, iv2, a13_*iv3);
    float ya2 = fmaf(a02_, iv0, a12_*iv1) + fmaf(a22_, iv2, a23_*iv3);
    float ya3 = fmaf(a03_, iv0, a13_*iv1) + fmaf(a23_, iv2, a33_*iv3);
    float quad = (fmaf(iv0, ya0, iv1*ya1) + fmaf(iv2, ya2, iv3*ya3)) * id;

    // softmax weight up to a wave-constant factor (cancels in normalize)
    float wi = __expf(-0.5f * quad) * rsd;

    // diagonal-R identity: mi = z − σ∘y  (y = S⁻¹ iv = ya·id)
    float y0 = ya0*id, y1 = ya1*id, y2 = ya2*id, y3 = ya3*id;
    float mi0 = fmaf(-sgc.x, y0, zz.x);
    float mi1 = fmaf(-sgc.y, y1, zz.y);
    float mi2 = fmaf(-sgc.z, y2, zz.z);
    float mi3 = fmaf(-sgc.w, y3, zz.w);

    const int par = t & 1;
    float* lb = xch[par];

    if (wv == 0) {
      // chains: W, wm0-3
      float cW  = wsum_v(wi);
      float cm0 = wsum_v(wi*mi0);
      float cm1 = wsum_v(wi*mi1);
      float cm2 = wsum_v(wi*mi2);
      float cm3 = wsum_v(wi*mi3);
      if (n == 63) {
        *(float4*)&lb[0] = make_float4(cW, cm0, cm1, cm2);
        lb[4] = cm3;
      }
    } else if (wv == 1) {
      // chains: q00,q01,q02,q03 ; X_rc = δσ − σ_r σ_c id a_rc + mi_r mi_c
      float t0 = sgc.x * id;
      float X00 = fmaf(mi0, mi0, sgc.x) - (t0*sgc.x)*a00_;
      float X01 = fmaf(mi0, mi1, -(t0*sgc.y)*a01_);
      float X02 = fmaf(mi0, mi2, -(t0*sgc.z)*a02_);
      float X03 = fmaf(mi0, mi3, -(t0*sgc.w)*a03_);
      float c00 = wsum_v(wi*X00);
      float c01 = wsum_v(wi*X01);
      float c02 = wsum_v(wi*X02);
      float c03 = wsum_v(wi*X03);
      if (n == 63) { lb[5]=c00; lb[6]=c01; lb[7]=c02; lb[8]=c03; }
    } else if (wv == 2) {
      // chains: q11,q12,q13
      float t1 = sgc.y * id;
      float X11 = fmaf(mi1, mi1, sgc.y) - (t1*sgc.y)*a11_;
      float X12 = fmaf(mi1, mi2, -(t1*sgc.z)*a12_);
      float X13 = fmaf(mi1, mi3, -(t1*sgc.w)*a13_);
      float c11 = wsum_v(wi*X11);
      float c12 = wsum_v(wi*X12);
      float c13 = wsum_v(wi*X13);
      if (n == 63) { lb[9]=c11; lb[10]=c12; lb[11]=c13; }
    } else {
      // chains: q22,q23,q33
      float t2 = sgc.z * id;
      float t3 = sgc.w * id;
      float X22 = fmaf(mi2, mi2, sgc.z) - (t2*sgc.z)*a22_;
      float X23 = fmaf(mi2, mi3, -(t2*sgc.w)*a23_);
      float X33 = fmaf(mi3, mi3, sgc.w) - (t3*sgc.w)*a33_;
      float c22 = wsum_v(wi*X22);
      float c23 = wsum_v(wi*X23);
      float c33 = wsum_v(wi*X33);
      if (n == 63) {
        *(float2*)&lb[12] = make_float2(c22, c23);
        lb[14] = c33;
      }
    }

    __syncthreads();

    A0 = *(const float4*)&xch[par][0];
    A1 = *(const float4*)&xch[par][4];
    A2 = *(const float4*)&xch[par][8];
    A3 = *(const float4*)&xch[par][12];

    if (wv == 0 && n == 0) {
      float* fp = &fr[((size_t)t*NB + fi)*16];
      *(float4*)&fp[0]  = A0;
      *(float4*)&fp[4]  = A1;
      *(float4*)&fp[8]  = A2;
      *(float4*)&fp[12] = A3;
    }
    zz = zn; sgc = sgn;
  }
}

// ==========================================================================
// Backward smoother as an affine suffix scan
// ==========================================================================
struct Map { float G[4][4]; float c[4]; float Dm[4][4]; };

__device__ __forceinline__ void map_identity(Map& M) {
#pragma unroll
  for (int r = 0; r < 4; ++r) {
    M.c[r] = 0.f;
#pragma unroll
    for (int cc = 0; cc < 4; ++cc) { M.G[r][cc] = (r==cc)?1.f:0.f; M.Dm[r][cc] = 0.f; }
  }
}

// R = F ∘ S (apply S first, then F); R may alias either arg
__device__ __forceinline__ void compose(const Map& F, const Map& Sm, Map& R) {
  float G[4][4], cv[4], V[4][4], Dn[4][4];
#pragma unroll
  for (int r = 0; r < 4; ++r)
#pragma unroll
    for (int c = 0; c < 4; ++c)
      G[r][c] = F.G[r][0]*Sm.G[0][c] + F.G[r][1]*Sm.G[1][c]
              + F.G[r][2]*Sm.G[2][c] + F.G[r][3]*Sm.G[3][c];
#pragma unroll
  for (int r = 0; r < 4; ++r)
    cv[r] = F.c[r] + F.G[r][0]*Sm.c[0] + F.G[r][1]*Sm.c[1]
                   + F.G[r][2]*Sm.c[2] + F.G[r][3]*Sm.c[3];
#pragma unroll
  for (int r = 0; r < 4; ++r)
#pragma unroll
    for (int c = 0; c < 4; ++c)
      V[r][c] = F.G[r][0]*Sm.Dm[0][c] + F.G[r][1]*Sm.Dm[1][c]
              + F.G[r][2]*Sm.Dm[2][c] + F.G[r][3]*Sm.Dm[3][c];
#pragma unroll
  for (int r = 0; r < 4; ++r)
#pragma unroll
    for (int c = r; c < 4; ++c) {
      float v = F.Dm[r][c] + V[r][0]*F.G[c][0] + V[r][1]*F.G[c][1]
                           + V[r][2]*F.G[c][2] + V[r][3]*F.G[c][3];
      Dn[r][c] = v; Dn[c][r] = v;
    }
#pragma unroll
  for (int r = 0; r < 4; ++r) {
    R.c[r] = cv[r];
#pragma unroll
    for (int c = 0; c < 4; ++c) { R.G[r][c] = G[r][c]; R.Dm[r][c] = Dn[r][c]; }
  }
}

// per-step map f_t for filter i (from raw forward results)
__device__ __forceinline__ void make_ft(int t, int i,
    const float* __restrict__ fr,
    const float A[4][4], const float b[4], const float Q[4][4], Map& M) {
  float mf[4], Pf[4][4];
  load_state_raw(&fr[((size_t)t*NB + i)*16], mf, Pf);
  float mp[4];
#pragma unroll
  for (int r = 0; r < 4; ++r)
    mp[r] = b[r] + A[r][0]*mf[0] + A[r][1]*mf[1] + A[r][2]*mf[2] + A[r][3]*mf[3];
  float AP[4][4];
#pragma unroll
  for (int r = 0; r < 4; ++r)
#pragma unroll
    for (int c = 0; c < 4; ++c)
      AP[r][c] = A[r][0]*Pf[0][c] + A[r][1]*Pf[1][c] + A[r][2]*Pf[2][c] + A[r][3]*Pf[3][c];
  float Pp[4][4];
#pragma unroll
  for (int r = 0; r < 4; ++r)
#pragma unroll
    for (int c = r; c < 4; ++c) {
      float v = Q[r][c] + AP[r][0]*A[c][0] + AP[r][1]*A[c][1]
                        + AP[r][2]*A[c][2] + AP[r][3]*A[c][3];
      Pp[r][c] = v; Pp[c][r] = v;
    }
  float Ppi[4][4];
  inv4(Pp, Ppi);
  float W[4][4]; // Pf A^T
#pragma unroll
  for (int r = 0; r < 4; ++r)
#pragma unroll
    for (int c = 0; c < 4; ++c)
      W[r][c] = Pf[r][0]*A[c][0] + Pf[r][1]*A[c][1] + Pf[r][2]*A[c][2] + Pf[r][3]*A[c][3];
#pragma unroll
  for (int r = 0; r < 4; ++r)
#pragma unroll
    for (int c = 0; c < 4; ++c)
      M.G[r][c] = W[r][0]*Ppi[0][c] + W[r][1]*Ppi[1][c] + W[r][2]*Ppi[2][c] + W[r][3]*Ppi[3][c];
#pragma unroll
  for (int r = 0; r < 4; ++r)
    M.c[r] = mf[r] - (M.G[r][0]*mp[0] + M.G[r][1]*mp[1] + M.G[r][2]*mp[2] + M.G[r][3]*mp[3]);
  float V[4][4];
#pragma unroll
  for (int r = 0; r < 4; ++r)
#pragma unroll
    for (int c = 0; c < 4; ++c)
      V[r][c] = M.G[r][0]*Pp[0][c] + M.G[r][1]*Pp[1][c] + M.G[r][2]*Pp[2][c] + M.G[r][3]*Pp[3][c];
#pragma unroll
  for (int r = 0; r < 4; ++r)
#pragma unroll
    for (int c = r; c < 4; ++c) {
      float v = Pf[r][c] - (V[r][0]*M.G[c][0] + V[r][1]*M.G[c][1]
                          + V[r][2]*M.G[c][2] + V[r][3]*M.G[c][3]);
      M.Dm[r][c] = v; M.Dm[c][r] = v;
    }
}

__device__ __forceinline__ void store_map(float* __restrict__ p, const Map& M) {
  *(float4*)&p[0]  = make_float4(M.G[0][0],M.G[0][1],M.G[0][2],M.G[0][3]);
  *(float4*)&p[4]  = make_float4(M.G[1][0],M.G[1][1],M.G[1][2],M.G[1][3]);
  *(float4*)&p[8]  = make_float4(M.G[2][0],M.G[2][1],M.G[2][2],M.G[2][3]);
  *(float4*)&p[12] = make_float4(M.G[3][0],M.G[3][1],M.G[3][2],M.G[3][3]);
  *(float4*)&p[16] = make_float4(M.c[0],M.c[1],M.c[2],M.c[3]);
  *(float4*)&p[20] = make_float4(M.Dm[0][0],M.Dm[0][1],M.Dm[0][2],M.Dm[0][3]);
  *(float4*)&p[24] = make_float4(M.Dm[1][0],M.Dm[1][1],M.Dm[1][2],M.Dm[1][3]);
  *(float4*)&p[28] = make_float4(M.Dm[2][0],M.Dm[2][1],M.Dm[2][2],M.Dm[2][3]);
  *(float4*)&p[32] = make_float4(M.Dm[3][0],M.Dm[3][1],M.Dm[3][2],M.Dm[3][3]);
}
__device__ __forceinline__ void load_map(const float* __restrict__ p, Map& M) {
  float4 g0=*(const float4*)&p[0], g1=*(const float4*)&p[4],
         g2=*(const float4*)&p[8], g3=*(const float4*)&p[12];
  float4 cv=*(const float4*)&p[16];
  float4 d0=*(const float4*)&p[20], d1=*(const float4*)&p[24],
         d2=*(const float4*)&p[28], d3=*(const float4*)&p[32];
  M.G[0][0]=g0.x;M.G[0][1]=g0.y;M.G[0][2]=g0.z;M.G[0][3]=g0.w;
  M.G[1][0]=g1.x;M.G[1][1]=g1.y;M.G[1][2]=g1.z;M.G[1][3]=g1.w;
  M.G[2][0]=g2.x;M.G[2][1]=g2.y;M.G[2][2]=g2.z;M.G[2][3]=g2.w;
  M.G[3][0]=g3.x;M.G[3][1]=g3.y;M.G[3][2]=g3.z;M.G[3][3]=g3.w;
  M.c[0]=cv.x;M.c[1]=cv.y;M.c[2]=cv.z;M.c[3]=cv.w;
  M.Dm[0][0]=d0.x;M.Dm[0][1]=d0.y;M.Dm[0][2]=d0.z;M.Dm[0][3]=d0.w;
  M.Dm[1][0]=d1.x;M.Dm[1][1]=d1.y;M.Dm[1][2]=d1.z;M.Dm[1][3]=d1.w;
  M.Dm[2][0]=d2.x;M.Dm[2][1]=d2.y;M.Dm[2][2]=d2.z;M.Dm[2][3]=d2.w;
  M.Dm[3][0]=d3.x;M.Dm[3][1]=d3.y;M.Dm[3][2]=d3.z;M.Dm[3][3]=d3.w;
}

// LDS map I/O, stride-37 floats (bank-conflict-free scalar layout)
__device__ __forceinline__ void store_map_lds(float* p, const Map& M) {
#pragma unroll
  for (int r = 0; r < 4; ++r) {
#pragma unroll
    for (int c2 = 0; c2 < 4; ++c2) {
      p[r*4+c2]    = M.G[r][c2];
      p[20+r*4+c2] = M.Dm[r][c2];
    }
    p[16+r] = M.c[r];
  }
}
__device__ __forceinline__ void load_map_lds(const float* p, Map& M) {
#pragma unroll
  for (int r = 0; r < 4; ++r) {
#pragma unroll
    for (int c2 = 0; c2 < 4; ++c2) {
      M.G[r][c2]  = p[r*4+c2];
      M.Dm[r][c2] = p[20+r*4+c2];
    }
    M.c[r] = p[16+r];
  }
}

// K3 phase A: per (chunk, filter) compose chunk aggregate right-to-left
__global__ void __launch_bounds__(64, 1) k_phaseA(
    const float* __restrict__ fr,
    const float* __restrict__ Ag, const float* __restrict__ bg,
    const float* __restrict__ qp, float* __restrict__ Cw) {
  const int cc = blockIdx.x;
  const int i  = threadIdx.x;
  float A[4][4], Q[4][4], b[4];
  load_A_b_Q(Ag, bg, qp, A, b, Q);
  Map agg; map_identity(agg);
  int a = cc * CLEN;
  int bb = a + CLEN - 1; if (bb > T - 2) bb = T - 2;
  for (int t = bb; t >= a; --t) {
    Map f; make_ft(t, i, fr, A, b, Q, f);
    compose(f, agg, agg);
  }
  store_map(&Cw[((size_t)i*CH + cc)*36], agg);
}

// K4 phase B: per filter, parallel Hillis-Steele suffix scan over CH chunks
__global__ void __launch_bounds__(CH, 1) k_phaseB(
    const float* __restrict__ Cw, float* __restrict__ Ew) {
  const int fi = blockIdx.x;
  const int cc = threadIdx.x;
  __shared__ float lds[CH * 37];

  Map M;
  load_map(&Cw[((size_t)fi*CH + cc)*36], M);
  store_map_lds(&lds[cc*37], M);
  __syncthreads();

#pragma unroll
  for (int k = 0; k < 8; ++k) {        // log2(CH) = 8
    int step = 1 << k;
    Map P;
    bool have = (cc + step < CH);
    if (have) load_map_lds(&lds[(cc+step)*37], P);
    __syncthreads();
    if (have) {
      compose(M, P, M);                // M spans [cc, cc+2^{k+1})
      store_map_lds(&lds[cc*37], M);
    }
    __syncthreads();
  }

  Map E;
  if (cc == CH - 1) map_identity(E);
  else              load_map_lds(&lds[(cc+1)*37], E);
  store_map(&Ew[((size_t)fi*CH + cc)*36], E);
}

// cholesky of sP+1e-5 I, z = sm + L eps, out = z @ dec_w + dec_b
__device__ __forceinline__ void recon(int t, int i,
    const float sm[4], const float sP[4][4],
    const float* __restrict__ eps, const float* __restrict__ dw,
    const float* __restrict__ db, float* __restrict__ out) {
  float a00 = sP[0][0]+1e-5f, a11 = sP[1][1]+1e-5f, a22 = sP[2][2]+1e-5f, a33 = sP[3][3]+1e-5f;
  float L00 = sqrtf(a00);
  float r0 = __fdividef(1.0f, L00);
  float L10 = sP[1][0]*r0, L20 = sP[2][0]*r0, L30 = sP[3][0]*r0;
  float L11 = sqrtf(a11 - L10*L10);
  float r1 = __fdividef(1.0f, L11);
  float L21 = (sP[2][1]-L20*L10)*r1, L31 = (sP[3][1]-L30*L10)*r1;
  float L22 = sqrtf(a22 - L20*L20 - L21*L21);
  float r2 = __fdividef(1.0f, L22);
  float L32 = (sP[3][2]-L30*L20-L31*L21)*r2;
  float L33 = sqrtf(a33 - L30*L30 - L31*L31 - L32*L32);
  float4 e = *(const float4*)&eps[((size_t)t*NB + i)*4];
  float z0 = sm[0] + L00*e.x;
  float z1 = sm[1] + L10*e.x + L11*e.y;
  float z2 = sm[2] + L20*e.x + L21*e.y + L22*e.z;
  float z3 = sm[3] + L30*e.x + L31*e.y + L32*e.z + L33*e.w;
#pragma unroll
  for (int p = 0; p < 3; ++p)
    out[((size_t)t*NB + i)*3 + p] =
        db[p] + z0*dw[0*3+p] + z1*dw[1*3+p] + z2*dw[2*3+p] + z3*dw[3*3+p];
}

// K5 phase C: apply exclusive suffix, walk chunk downward emitting recon
__global__ void __launch_bounds__(64, 1) k_phaseC(
    const float* __restrict__ fr,
    const float* __restrict__ Ew,
    const float* __restrict__ Ag, const float* __restrict__ bg,
    const float* __restrict__ qp,
    const float* __restrict__ eps, const float* __restrict__ dw,
    const float* __restrict__ db, float* __restrict__ out) {
  const int cc = blockIdx.x;
  const int i  = threadIdx.x;
  float A[4][4], Q[4][4], b[4];
  load_A_b_Q(Ag, bg, qp, A, b, Q);

  // final filtered state (t = T-1) == final smoothed state
  float mT[4], PT[4][4];
  load_state_raw(&fr[((size_t)(T-1)*NB + i)*16], mT, PT);

  Map E; load_map(&Ew[((size_t)i*CH + cc)*36], E);

  float sm[4], sP[4][4];
#pragma unroll
  for (int r = 0; r < 4; ++r)
    sm[r] = E.c[r] + E.G[r][0]*mT[0] + E.G[r][1]*mT[1] + E.G[r][2]*mT[2] + E.G[r][3]*mT[3];
  {
    float V[4][4];
#pragma unroll
    for (int r = 0; r < 4; ++r)
#pragma unroll
      for (int c = 0; c < 4; ++c)
        V[r][c] = E.G[r][0]*PT[0][c] + E.G[r][1]*PT[1][c] + E.G[r][2]*PT[2][c] + E.G[r][3]*PT[3][c];
#pragma unroll
    for (int r = 0; r < 4; ++r)
#pragma unroll
      for (int c = r; c < 4; ++c) {
        float v = E.Dm[r][c] + V[r][0]*E.G[c][0] + V[r][1]*E.G[c][1]
                             + V[r][2]*E.G[c][2] + V[r][3]*E.G[c][3];
        sP[r][c] = v; sP[c][r] = v;
      }
  }

  if (cc == CH - 1) recon(T - 1, i, mT, PT, eps, dw, db, out);

  int a = cc * CLEN;
  int bb = a + CLEN - 1; if (bb > T - 2) bb = T - 2;
  for (int t = bb; t >= a; --t) {
    Map f; make_ft(t, i, fr, A, b, Q, f);
    float smn[4];
#pragma unroll
    for (int r = 0; r < 4; ++r)
      smn[r] = f.c[r] + f.G[r][0]*sm[0] + f.G[r][1]*sm[1] + f.G[r][2]*sm[2] + f.G[r][3]*sm[3];
    float V[4][4];
#pragma unroll
    for (int r = 0; r < 4; ++r)
#pragma unroll
      for (int c = 0; c < 4; ++c)
        V[r][c] = f.G[r][0]*sP[0][c] + f.G[r][1]*sP[1][c] + f.G[r][2]*sP[2][c] + f.G[r][3]*sP[3][c];
#pragma unroll
    for (int r = 0; r < 4; ++r)
#pragma unroll
      for (int c = r; c < 4; ++c) {
        float v = f.Dm[r][c] + V[r][0]*f.G[c][0] + V[r][1]*f.G[c][1]
                             + V[r][2]*f.G[c][2] + V[r][3]*f.G[c][3];
        sP[r][c] = v; sP[c][r] = v;
      }
    sm[0]=smn[0]; sm[1]=smn[1]; sm[2]=smn[2]; sm[3]=smn[3];
    recon(t, i, sm, sP, eps, dw, db, out);
  }
}

// ==========================================================================
extern "C" void kernel_launch(void* const* d_in, const int* in_sizes, int n_in,
                              void* d_out, int out_size, void* d_ws, size_t ws_size,
                              hipStream_t stream) {
  const float* x   = (const float*)d_in[0];
  const float* eps = (const float*)d_in[1];
  const float* w1  = (const float*)d_in[2];
  const float* b1  = (const float*)d_in[3];
  const float* wx  = (const float*)d_in[4];
  const float* bx  = (const float*)d_in[5];
  const float* wl  = (const float*)d_in[6];
  const float* bl  = (const float*)d_in[7];
  const float* dw  = (const float*)d_in[8];
  const float* db  = (const float*)d_in[9];
  const float* Ag  = (const float*)d_in[10];
  const float* bg  = (const float*)d_in[11];
  const float* qp  = (const float*)d_in[12];

  float* ws    = (float*)d_ws;
  float* xhat  = ws + OFF_XHAT;
  float* sigma = ws + OFF_SIGMA;
  float* fr    = ws + OFF_FR;
  float* Cw    = ws + OFF_C;
  float* Ew    = ws + OFF_E;
  float* out   = (float*)d_out;

  k_encoder<<<(TP1*NB + 255)/256, 256, 0, stream>>>(x, w1, b1, wx, bx, wl, bl, xhat, sigma);
  k_filter<<<NB, 256, 0, stream>>>(xhat, sigma, Ag, bg, qp, fr);
  k_phaseA<<<CH, NB, 0, stream>>>(fr, Ag, bg, qp, Cw);
  k_phaseB<<<NB, CH, 0, stream>>>(Cw, Ew);
  k_phaseC<<<CH, NB, 0, stream>>>(fr, Ew, Ag, bg, qp, eps, dw, db, out);
}